// Round 12
// baseline (744.847 us; speedup 1.0000x reference)
//
#include <hip/hip_runtime.h>
#include <math.h>

#define PI_F 3.14159265358979323846f

// ---------------------------------------------------------------------------
// N_ORDER=256, PRED_LEN=192, SEQ_LEN=768, ENC_IN=21, B=16, L_s=192<<s, MODES=32
//
// Pipeline (all linear in x; kernel-matrix construction then one apply):
//   w_d = A^d B                      (doubling chain, 10 levels)
//   Wt[(s,ri,k)][i][o] = W[i][o][k]  (transpose, LDS-staged)
//   Y[z][p][i] = sum_o Wt[z][i][o] E[L-192+p][o]           (GEMM, 4.8 GF)
//   Qb[s][d][n] = sum_i w_d[i] Y[n][i],  n=(ri,k,p)        (GEMM, 8.5 GF)
//   Z[k][d][p] = sum_{d'<=d} e^{-2pi i k d'/L} Q[k][d'][p] (chunked scan,
//                16<<s chunks of 12)
//   Ktil[s][sidx][p] = sum_k c_k Re(e^{2pi i k((191-sidx)%L)/L} Z[k][L-1-sidx][p])
//                      (fused scan pass 2 + k-reduction, one block per chunk)
//   Ktot[tau][p] = sum_s mlp_w[s] Ktil[s][tau-(768-L_s)][p]
//   out[b][p][c] = sum_tau x[b][tau][c] Ktot[tau][p] + mlp_b
//
// Workspace layout (float offsets):
//   w    [s][d][i]        : 0        len 344064
//   Apow [s][2][65536]    : 344064   len 393216
//   Ktil [s][sidx][p]     : 737280   len 258048
//   Ktot [tau][p]         : 995328   len 147456
//   Y    [z][p][i]        : 1142784  len 9437184   (dead after k_gemm_Q4;
//        S (chunk sums)   : 1142784  len 9437184    reused: 3*32*64*384)
//   QT region (time-shared):
//     Wt [z][i][o]        : 10579968 len 12582912
//     Qb [s][d][12288]    : 10579968 len 16515072
// Total 27,095,040 floats (proven to fit)
// ---------------------------------------------------------------------------
#define W_OFF    0
#define AP_OFF   344064
#define KT_OFF   737280
#define KTOT_OFF 995328
#define Y_OFF    1142784
#define S_OFF    1142784
#define QT_OFF   10579968
#define WS_FLOATS 27095040

__device__ __forceinline__ int off_w_f(int s)  { return 49152  * ((1 << s) - 1); }
__device__ __forceinline__ int qoff_f(int s)   { return 2359296 * ((1 << s) - 1); }
__device__ __forceinline__ int ktoff_f(int s)  { return 36864  * ((1 << s) - 1); }

// ---------------------------------------------------------------------------
// Legacy 64x64 tile GEMM (used only by the small doubling-chain kernels).
// ---------------------------------------------------------------------------
template<bool BT>
__device__ __forceinline__ void gemm_tile(const float* __restrict__ A,
                                          const float* __restrict__ B,
                                          float* __restrict__ C,
                                          int M, int N, int ldc, int m0, int n0)
{
    __shared__ float As[16][68];
    __shared__ float Bs[16][68];
    const int tid = threadIdx.x;
    const int tx = tid & 15;
    const int ty = tid >> 4;
    const int r  = tid >> 2;
    const int kq = (tid & 3) << 2;

    float acc[4][4] = {{0.f,0.f,0.f,0.f},{0.f,0.f,0.f,0.f},
                       {0.f,0.f,0.f,0.f},{0.f,0.f,0.f,0.f}};

    for (int kk = 0; kk < 256; kk += 16) {
        float4 av = make_float4(0.f, 0.f, 0.f, 0.f);
        if (m0 + r < M)
            av = *(const float4*)(A + (size_t)(m0 + r) * 256 + kk + kq);
        As[kq + 0][r] = av.x; As[kq + 1][r] = av.y;
        As[kq + 2][r] = av.z; As[kq + 3][r] = av.w;

        if (BT) {
            float4 bv = make_float4(0.f, 0.f, 0.f, 0.f);
            if (n0 + r < N)
                bv = *(const float4*)(B + (size_t)(n0 + r) * 256 + kk + kq);
            Bs[kq + 0][r] = bv.x; Bs[kq + 1][r] = bv.y;
            Bs[kq + 2][r] = bv.z; Bs[kq + 3][r] = bv.w;
        } else {
            const int kb = tid >> 4;
            const int j4 = (tid & 15) << 2;
            float4 bv = *(const float4*)(B + (size_t)(kk + kb) * 256 + n0 + j4);
            *(float4*)(&Bs[kb][j4]) = bv;
        }
        __syncthreads();

        #pragma unroll
        for (int k = 0; k < 16; ++k) {
            float4 a4 = *(const float4*)(&As[k][ty << 2]);
            float4 b4 = *(const float4*)(&Bs[k][tx << 2]);
            acc[0][0] = fmaf(a4.x, b4.x, acc[0][0]);
            acc[0][1] = fmaf(a4.x, b4.y, acc[0][1]);
            acc[0][2] = fmaf(a4.x, b4.z, acc[0][2]);
            acc[0][3] = fmaf(a4.x, b4.w, acc[0][3]);
            acc[1][0] = fmaf(a4.y, b4.x, acc[1][0]);
            acc[1][1] = fmaf(a4.y, b4.y, acc[1][1]);
            acc[1][2] = fmaf(a4.y, b4.z, acc[1][2]);
            acc[1][3] = fmaf(a4.y, b4.w, acc[1][3]);
            acc[2][0] = fmaf(a4.z, b4.x, acc[2][0]);
            acc[2][1] = fmaf(a4.z, b4.y, acc[2][1]);
            acc[2][2] = fmaf(a4.z, b4.z, acc[2][2]);
            acc[2][3] = fmaf(a4.z, b4.w, acc[2][3]);
            acc[3][0] = fmaf(a4.w, b4.x, acc[3][0]);
            acc[3][1] = fmaf(a4.w, b4.y, acc[3][1]);
            acc[3][2] = fmaf(a4.w, b4.z, acc[3][2]);
            acc[3][3] = fmaf(a4.w, b4.w, acc[3][3]);
        }
        __syncthreads();
    }

    #pragma unroll
    for (int u = 0; u < 4; ++u) {
        int row = m0 + (ty << 2) + u;
        if (row < M) {
            float4 cv = make_float4(acc[u][0], acc[u][1], acc[u][2], acc[u][3]);
            *(float4*)(C + (size_t)row * ldc + n0 + (tx << 2)) = cv;
        }
    }
}

// ---------------------------------------------------------------------------
// Q workhorse (r7-proven): C[64][128] = A[64][256] @ B^T, K=256, 256 threads,
// 4x8 microtile, single-buffered.  A pre-offset to (m0,0), stride 256, K
// fastest.  B rows are output cols (pre-offset n0), stride 256, K fastest.
// ---------------------------------------------------------------------------
__device__ __forceinline__ void gemm64x128_q(const float* __restrict__ A,
                                             const float* __restrict__ B,
                                             float* __restrict__ C, int ldc)
{
    __shared__ float As[16][68];
    __shared__ float Bs[16][132];

    const int tid = threadIdx.x;
    const int tx = tid & 15;
    const int ty = tid >> 4;
    const int ra  = tid >> 2;          // 0..63
    const int kqa = (tid & 3) << 2;    // 0,4,8,12
    const int rb  = tid >> 1;          // 0..127
    const int kq8 = (tid & 1) << 3;    // 0 or 8

    float acc[2][4][4];                // [colgrp g][row u][v]
    #pragma unroll
    for (int g = 0; g < 2; ++g)
        #pragma unroll
        for (int u = 0; u < 4; ++u)
            #pragma unroll
            for (int v = 0; v < 4; ++v) acc[g][u][v] = 0.f;

    for (int kk = 0; kk < 256; kk += 16) {
        float4 av = *(const float4*)(A + (size_t)ra * 256 + kk + kqa);
        As[kqa + 0][ra] = av.x; As[kqa + 1][ra] = av.y;
        As[kqa + 2][ra] = av.z; As[kqa + 3][ra] = av.w;

        const float* bp = B + (size_t)rb * 256 + kk + kq8;
        float4 b0 = *(const float4*)(bp);
        float4 b1 = *(const float4*)(bp + 4);
        Bs[kq8 + 0][rb] = b0.x; Bs[kq8 + 1][rb] = b0.y;
        Bs[kq8 + 2][rb] = b0.z; Bs[kq8 + 3][rb] = b0.w;
        Bs[kq8 + 4][rb] = b1.x; Bs[kq8 + 5][rb] = b1.y;
        Bs[kq8 + 6][rb] = b1.z; Bs[kq8 + 7][rb] = b1.w;
        __syncthreads();

        #pragma unroll
        for (int kq = 0; kq < 16; ++kq) {
            float4 a   = *(const float4*)(&As[kq][4 * ty]);
            float4 b0v = *(const float4*)(&Bs[kq][4 * tx]);
            float4 b1v = *(const float4*)(&Bs[kq][4 * tx + 64]);
            float af[4] = {a.x, a.y, a.z, a.w};
            float bf[8] = {b0v.x, b0v.y, b0v.z, b0v.w, b1v.x, b1v.y, b1v.z, b1v.w};
            #pragma unroll
            for (int g = 0; g < 2; ++g)
                #pragma unroll
                for (int u = 0; u < 4; ++u)
                    #pragma unroll
                    for (int v = 0; v < 4; ++v)
                        acc[g][u][v] = fmaf(af[u], bf[g * 4 + v], acc[g][u][v]);
        }
        __syncthreads();
    }

    #pragma unroll
    for (int u = 0; u < 4; ++u) {
        int row = 4 * ty + u;
        #pragma unroll
        for (int g = 0; g < 2; ++g) {
            float4 cv = make_float4(acc[g][u][0], acc[g][u][1],
                                    acc[g][u][2], acc[g][u][3]);
            *(float4*)(C + (size_t)row * ldc + 4 * tx + 64 * g) = cv;
        }
    }
}

// ---------------------------------------------------------------------------
// Y workhorse (r10-proven): 64x128 tile, 128 threads, 8x8 microtile.
// ---------------------------------------------------------------------------
__device__ __forceinline__ void gemm64x128_y(const float* __restrict__ A,
                                             const float* __restrict__ B,
                                             float* __restrict__ C, int ldc)
{
    __shared__ float As[16][68];
    __shared__ float Bs[16][132];

    const int tid = threadIdx.x;       // 0..127
    const int tx  = tid & 15;
    const int ty  = tid >> 4;          // 0..7
    const int ra  = tid >> 1;          // 0..63
    const int kq8 = (tid & 1) << 3;

    float acc[2][2][4][4];
    #pragma unroll
    for (int h = 0; h < 2; ++h)
        #pragma unroll
        for (int g = 0; g < 2; ++g)
            #pragma unroll
            for (int u = 0; u < 4; ++u)
                #pragma unroll
                for (int v = 0; v < 4; ++v) acc[h][g][u][v] = 0.f;

    for (int kk = 0; kk < 256; kk += 16) {
        const float* ap = A + (size_t)ra * 256 + kk + kq8;
        float4 a0 = *(const float4*)(ap);
        float4 a1 = *(const float4*)(ap + 4);
        As[kq8 + 0][ra] = a0.x; As[kq8 + 1][ra] = a0.y;
        As[kq8 + 2][ra] = a0.z; As[kq8 + 3][ra] = a0.w;
        As[kq8 + 4][ra] = a1.x; As[kq8 + 5][ra] = a1.y;
        As[kq8 + 6][ra] = a1.z; As[kq8 + 7][ra] = a1.w;

        const float* bp = B + (size_t)tid * 256 + kk;
        float4 b0 = *(const float4*)(bp);
        float4 b1 = *(const float4*)(bp + 4);
        float4 b2 = *(const float4*)(bp + 8);
        float4 b3 = *(const float4*)(bp + 12);
        Bs[ 0][tid] = b0.x; Bs[ 1][tid] = b0.y; Bs[ 2][tid] = b0.z; Bs[ 3][tid] = b0.w;
        Bs[ 4][tid] = b1.x; Bs[ 5][tid] = b1.y; Bs[ 6][tid] = b1.z; Bs[ 7][tid] = b1.w;
        Bs[ 8][tid] = b2.x; Bs[ 9][tid] = b2.y; Bs[10][tid] = b2.z; Bs[11][tid] = b2.w;
        Bs[12][tid] = b3.x; Bs[13][tid] = b3.y; Bs[14][tid] = b3.z; Bs[15][tid] = b3.w;
        __syncthreads();

        #pragma unroll
        for (int kq = 0; kq < 16; ++kq) {
            float4 aA = *(const float4*)(&As[kq][4 * ty]);
            float4 aB = *(const float4*)(&As[kq][4 * ty + 32]);
            float4 bA = *(const float4*)(&Bs[kq][4 * tx]);
            float4 bB = *(const float4*)(&Bs[kq][4 * tx + 64]);
            float af[8] = {aA.x, aA.y, aA.z, aA.w, aB.x, aB.y, aB.z, aB.w};
            float bf[8] = {bA.x, bA.y, bA.z, bA.w, bB.x, bB.y, bB.z, bB.w};
            #pragma unroll
            for (int h = 0; h < 2; ++h)
                #pragma unroll
                for (int u = 0; u < 4; ++u)
                    #pragma unroll
                    for (int g = 0; g < 2; ++g)
                        #pragma unroll
                        for (int v = 0; v < 4; ++v)
                            acc[h][g][u][v] = fmaf(af[h * 4 + u], bf[g * 4 + v],
                                                   acc[h][g][u][v]);
        }
        __syncthreads();
    }

    #pragma unroll
    for (int h = 0; h < 2; ++h)
        #pragma unroll
        for (int u = 0; u < 4; ++u) {
            int row = 4 * ty + 32 * h + u;
            #pragma unroll
            for (int g = 0; g < 2; ++g) {
                float4 cv = make_float4(acc[h][g][u][0], acc[h][g][u][1],
                                        acc[h][g][u][2], acc[h][g][u][3]);
                *(float4*)(C + (size_t)row * ldc + 4 * tx + 64 * g) = cv;
            }
        }
}

// ---------------------------------------------------------------------------
__global__ void k_init(const float* B0, const float* B1, const float* B2, float* ws)
{
    int s = blockIdx.x;
    const float* Bv = (s == 0) ? B0 : (s == 1) ? B1 : B2;
    ws[W_OFF + off_w_f(s) + threadIdx.x] = Bv[threadIdx.x];
}

// ---------------------------------------------------------------------------
// doubling level n: jump w[2^n + r] = Apow_n @ w[r]; square Apow_{n+1}
// ---------------------------------------------------------------------------
__global__ void k_level(int n, const float* A0, const float* A1, const float* A2,
                        float* ws)
{
    int s = blockIdx.z;
    int L = 192 << s;
    const float* Ain = (s == 0) ? A0 : (s == 1) ? A1 : A2;
    float* wbase = ws + W_OFF + off_w_f(s);
    float* bufA  = ws + AP_OFF + s * 131072;
    float* bufB  = bufA + 65536;
    const float* src = (n == 0) ? Ain : (((n - 1) & 1) ? bufB : bufA);

    int y = blockIdx.y;
    if (y < 4) {
        int p2 = 1 << n;
        if (p2 >= L) return;
        int cnt = min(p2, L - p2);
        int m0 = y * 64;
        if (m0 >= cnt) return;
        gemm_tile<true>(wbase, src, wbase + (size_t)p2 * 256,
                        cnt, 256, 256, m0, blockIdx.x * 64);
    } else {
        if ((2 << n) >= L) return;
        float* dst = (n & 1) ? bufB : bufA;
        gemm_tile<false>(src, src, dst, 256, 256, 256, (y - 4) * 64, blockIdx.x * 64);
    }
}

// ---------------------------------------------------------------------------
// Wt[s][ri][k][i][o] = W[i][o][k]  — LDS-staged, fully coalesced.
// ---------------------------------------------------------------------------
__global__ void k_transpose(const float* Wr0, const float* Wi0,
                            const float* Wr1, const float* Wi1,
                            const float* Wr2, const float* Wi2, float* ws)
{
    __shared__ float t[256][33];
    int bid = blockIdx.x;
    int i  = bid & 255;
    int ri = (bid >> 8) & 1;
    int s  = bid >> 9;
    const float* W;
    if (s == 0)      W = ri ? Wi0 : Wr0;
    else if (s == 1) W = ri ? Wi1 : Wr1;
    else             W = ri ? Wi2 : Wr2;

    const int tid = threadIdx.x;
    const float* slab = W + (size_t)i * 8192;
    #pragma unroll
    for (int j = 0; j < 8; ++j) {
        int f = j * 1024 + tid * 4;
        float4 v = *(const float4*)(slab + f);
        int o = f >> 5;
        int k = f & 31;
        t[o][k + 0] = v.x; t[o][k + 1] = v.y;
        t[o][k + 2] = v.z; t[o][k + 3] = v.w;
    }
    __syncthreads();

    int sri = s * 2 + ri;
    #pragma unroll
    for (int k = 0; k < 32; ++k) {
        ws[QT_OFF + (size_t)(sri * 32 + k) * 65536 + (size_t)i * 256 + tid] = t[tid][k];
    }
}

// ---------------------------------------------------------------------------
// Y[z][p][i] = sum_o E[L-192+p][o] * Wt[z][i][o]
// grid (128, 3, 3): x = (zz<<1)|ihalf, y = p-tile, z = s.  128 threads.
// ---------------------------------------------------------------------------
__global__ void __launch_bounds__(128, 4)
k_gemm_Y4(const float* E0, const float* E1, const float* E2, float* __restrict__ ws)
{
    const int s  = blockIdx.z;
    const int L  = 192 << s;
    const int zz = blockIdx.x >> 1;              // 0..63
    const int n0 = (blockIdx.x & 1) * 128;       // i half
    const int z  = s * 64 + zz;
    const int m0 = blockIdx.y * 64;              // p tile
    const float* E = (s == 0) ? E0 : (s == 1) ? E1 : E2;

    const float* Ap = E + (size_t)(L - 192) * 256 + (size_t)m0 * 256;
    const float* Bp = ws + QT_OFF + (size_t)z * 65536 + (size_t)n0 * 256;
    float* Cp = ws + Y_OFF + (size_t)z * 49152 + (size_t)m0 * 256 + n0;
    gemm64x128_y(Ap, Bp, Cp, 256);
}

// ---------------------------------------------------------------------------
// Qb[s][d][n] = sum_i w[s][d][i] * Y[n][i],  n = (ri*32+k)*192+p
// Y rows n at Y_OFF + s*3145728 + n*256, i (=K) fastest.
// grid (96, 21): x = 128-col tile of n, y = packed (s, d-tile).  256 threads.
// ---------------------------------------------------------------------------
__global__ void __launch_bounds__(256, 4)
k_gemm_Q4(float* __restrict__ ws)
{
    const int y = blockIdx.y;
    int s, yt;
    if (y < 3)      { s = 0; yt = y; }
    else if (y < 9) { s = 1; yt = y - 3; }
    else            { s = 2; yt = y - 9; }
    const int m0 = yt * 64;
    const int n0 = blockIdx.x * 128;

    const float* Ap = ws + W_OFF + off_w_f(s) + (size_t)m0 * 256;
    const float* Bp = ws + Y_OFF + (size_t)s * 3145728 + (size_t)n0 * 256;
    float* Cp = ws + QT_OFF + qoff_f(s) + (size_t)m0 * 12288 + n0;
    gemm64x128_q(Ap, Bp, Cp, 12288);
}

// ---------------------------------------------------------------------------
// Pass 1 of chunked twiddled scan: complex chunk sums, 16<<s chunks of 12.
// S[((s*32+k)*64 + c)*384 + {p, 192+p}] = chunk sum (re, im).
// grid (64, 32, 3), block 192 (= p); blocks with c >= 16<<s exit.
// ---------------------------------------------------------------------------
__global__ void k_scanA(float* __restrict__ ws)
{
    const int c = blockIdx.x;
    const int k = blockIdx.y;
    const int s = blockIdx.z;
    const int NC = 16 << s;
    if (c >= NC) return;
    const int L = 192 << s;
    const int p = threadIdx.x;

    __shared__ float twc[768], tws[768];
    for (int m = p; m < L; m += 192) {
        float ang = -2.f * PI_F * (float)m / (float)L;
        float ss, cc; sincosf(ang, &ss, &cc);
        twc[m] = cc; tws[m] = ss;
    }
    __syncthreads();

    const float* Qr = ws + QT_OFF + qoff_f(s) + (size_t)k * 192;
    const float* Qi = Qr + 6144;

    float ar = 0.f, ai = 0.f;
    const int d0 = c * 12;
    int ph = (k * d0) % L;
    #pragma unroll
    for (int j = 0; j < 12; ++j) {
        int d = d0 + j;
        float qr = Qr[(size_t)d * 12288 + p];
        float qi = Qi[(size_t)d * 12288 + p];
        float cc = twc[ph], sn = tws[ph];
        ar = fmaf(cc, qr, fmaf(-sn, qi, ar));
        ai = fmaf(cc, qi, fmaf( sn, qr, ai));
        ph += k; if (ph >= L) ph -= L;
    }
    size_t sb = (size_t)((s * 32 + k) * 64 + c) * 384;
    ws[S_OFF + sb + p]       = ar;
    ws[S_OFF + sb + 192 + p] = ai;
}

// ---------------------------------------------------------------------------
// Fused pass 2 + k-reduction: one block per (chunk c, scale s).
// For each k: offset = sum of earlier chunk sums, rescan own 12-step chunk,
// fold phase, accumulate over k into fa[12]; write Ktil directly.
// Replaces the old scanB (F writes) + kred entirely.
// grid (64, 3), block 192.
// ---------------------------------------------------------------------------
__global__ void k_scanBR(float* __restrict__ ws)
{
    const int c = blockIdx.x;
    const int s = blockIdx.y;
    const int NC = 16 << s;
    if (c >= NC) return;
    const int L = 192 << s;
    const int p = threadIdx.x;

    __shared__ float twc[768], tws[768];
    for (int m = p; m < L; m += 192) {
        float ang = -2.f * PI_F * (float)m / (float)L;
        float ss, cc; sincosf(ang, &ss, &cc);
        twc[m] = cc; tws[m] = ss;
    }
    __syncthreads();

    float fa[12];
    #pragma unroll
    for (int j = 0; j < 12; ++j) fa[j] = 0.f;

    const int d0 = c * 12;
    int m1 = d0 + 192 - L; if (m1 < 0) m1 += L;   // (d0 + 192) mod L

    for (int k = 0; k < 32; ++k) {
        float ar = 0.f, ai = 0.f;
        size_t sbase = (size_t)((s * 32 + k) * 64) * 384;
        for (int c2 = 0; c2 < c; ++c2) {
            ar += ws[S_OFF + sbase + (size_t)c2 * 384 + p];
            ai += ws[S_OFF + sbase + (size_t)c2 * 384 + 192 + p];
        }

        const float ck = ((k == 0) ? 1.f : 2.f) / (float)L;
        const float* Qr = ws + QT_OFF + qoff_f(s) + (size_t)k * 192;
        const float* Qi = Qr + 6144;

        int ph  = (k * d0) % L;
        int ph2 = (k * m1) % L;
        #pragma unroll
        for (int j = 0; j < 12; ++j) {
            int d = d0 + j;
            float qr = Qr[(size_t)d * 12288 + p];
            float qi = Qi[(size_t)d * 12288 + p];
            float cc = twc[ph], sn = tws[ph];
            ar = fmaf(cc, qr, fmaf(-sn, qi, ar));
            ai = fmaf(cc, qi, fmaf( sn, qr, ai));
            float f = ck * fmaf(twc[ph2], ar, tws[ph2] * ai);
            fa[j] += f;
            ph  += k; if (ph  >= L) ph  -= L;
            ph2 += k; if (ph2 >= L) ph2 -= L;
        }
    }

    float* Kt = ws + KT_OFF + ktoff_f(s);
    #pragma unroll
    for (int j = 0; j < 12; ++j) {
        int sidx = L - 1 - (d0 + j);
        Kt[(size_t)sidx * 192 + p] = fa[j];
    }
}

// ---------------------------------------------------------------------------
__global__ void k_combine(float* ws, const float* mw)
{
    int idx = blockIdx.x * 256 + threadIdx.x;
    if (idx >= 147456) return;
    int tau = idx / 192;
    int p   = idx - tau * 192;
    float sum = 0.f;
    #pragma unroll
    for (int s = 0; s < 3; ++s) {
        int L = 192 << s;
        int off = 768 - L;
        if (tau >= off)
            sum = fmaf(mw[s], ws[KT_OFF + ktoff_f(s) + (size_t)(tau - off) * 192 + p], sum);
    }
    ws[KTOT_OFF + idx] = sum;
}

// ---------------------------------------------------------------------------
__global__ void k_out(const float* __restrict__ x, const float* __restrict__ ws,
                      const float* __restrict__ mb, float* __restrict__ out)
{
    int bid = blockIdx.x;
    int b = bid / 21;
    int c = bid - b * 21;
    __shared__ float xl[768];
    for (int t = threadIdx.x; t < 768; t += 192)
        xl[t] = x[((size_t)b * 768 + t) * 21 + c];
    __syncthreads();

    int p = threadIdx.x;
    const float* K = ws + KTOT_OFF;
    float acc = 0.f;
    for (int tau = 0; tau < 768; ++tau)
        acc = fmaf(xl[tau], K[(size_t)tau * 192 + p], acc);
    out[((size_t)b * 192 + p) * 21 + c] = acc + mb[0];
}

// ---------------------------------------------------------------------------
extern "C" void kernel_launch(void* const* d_in, const int* in_sizes, int n_in,
                              void* d_out, int out_size, void* d_ws, size_t ws_size,
                              hipStream_t stream)
{
    const float* x   = (const float*)d_in[0];
    const float* A0  = (const float*)d_in[1];
    const float* B0  = (const float*)d_in[2];
    const float* E0  = (const float*)d_in[3];
    const float* Wr0 = (const float*)d_in[4];
    const float* Wi0 = (const float*)d_in[5];
    const float* A1  = (const float*)d_in[6];
    const float* B1  = (const float*)d_in[7];
    const float* E1  = (const float*)d_in[8];
    const float* Wr1 = (const float*)d_in[9];
    const float* Wi1 = (const float*)d_in[10];
    const float* A2  = (const float*)d_in[11];
    const float* B2  = (const float*)d_in[12];
    const float* E2  = (const float*)d_in[13];
    const float* Wr2 = (const float*)d_in[14];
    const float* Wi2 = (const float*)d_in[15];
    const float* mw  = (const float*)d_in[16];
    const float* mb  = (const float*)d_in[17];
    float* ws  = (float*)d_ws;
    float* out = (float*)d_out;

    if (ws_size < (size_t)WS_FLOATS * sizeof(float)) {
        hipMemsetAsync(d_out, 0, (size_t)out_size * sizeof(float), stream);
        return;
    }

    k_init<<<3, 256, 0, stream>>>(B0, B1, B2, ws);
    for (int n = 0; n < 10; ++n)
        k_level<<<dim3(4, 8, 3), 256, 0, stream>>>(n, A0, A1, A2, ws);
    k_transpose<<<1536, 256, 0, stream>>>(Wr0, Wi0, Wr1, Wi1, Wr2, Wi2, ws);
    k_gemm_Y4<<<dim3(128, 3, 3), 128, 0, stream>>>(E0, E1, E2, ws);
    k_gemm_Q4<<<dim3(96, 21), 256, 0, stream>>>(ws);
    k_scanA<<<dim3(64, 32, 3), 192, 0, stream>>>(ws);
    k_scanBR<<<dim3(64, 3), 192, 0, stream>>>(ws);
    k_combine<<<576, 256, 0, stream>>>(ws, mw);
    k_out<<<336, 192, 0, stream>>>(x, ws, mb, out);
}

// Round 13
// 430.513 us; speedup vs baseline: 1.7301x; 1.7301x over previous
//
#include <hip/hip_runtime.h>
#include <math.h>

#define PI_F 3.14159265358979323846f

// ---------------------------------------------------------------------------
// N_ORDER=256, PRED_LEN=192, SEQ_LEN=768, ENC_IN=21, B=16, L_s=192<<s, MODES=32
//
// Pipeline (all linear in x; kernel-matrix construction then one apply):
//   w_d = A^d B                      (doubling chain, 10 levels)
//   Wt[(s,ri,k)][i][o] = W[i][o][k]  (transpose, LDS-staged)
//   Y[z][p][i] = sum_o Wt[z][i][o] E[L-192+p][o]           (GEMM, 4.8 GF)
//   Qb[s][d][n] = sum_i w_d[i] Y[n][i],  n=(ri,k,p)        (GEMM, 8.5 GF)
//   Z[k][d][p] = sum_{d'<=d} e^{-2pi i k d'/L} Q[k][d'][p] (chunked scan)
//   F[s][sidx][k][p] = c_k Re(e^{2pi i k((191-sidx)%L)/L} Z[k][L-1-sidx][p])
//   Ktil[s][sidx][p] = sum_k F
//   Ktot[tau][p] = sum_s mlp_w[s] Ktil[s][tau-(768-L_s)][p]
//   out[b][p][c] = sum_tau x[b][tau][c] Ktot[tau][p] + mlp_b
//
// Workspace layout (float offsets):
//   w    [s][d][i]        : 0        len 344064
//   Apow [s][2][65536]    : 344064   len 393216
//   Ktil [s][sidx][p]     : 737280   len 258048
//   Ktot [tau][p]         : 995328   len 147456
//   Y    [z][p][i]        : 1142784  len 9437184   (dead after k_gemm_Q4;
//        S (chunk sums)   : 1142784  len 589824     reused by scan)
//        F (folded)       : 1732608  len 8257536
//   QT region (time-shared):
//     Wt [z][i][o]        : 10579968 len 12582912
//     Qb [s][d][12288]    : 10579968 len 16515072
// Total 27,095,040 floats (proven to fit)
// ---------------------------------------------------------------------------
#define W_OFF    0
#define AP_OFF   344064
#define KT_OFF   737280
#define KTOT_OFF 995328
#define Y_OFF    1142784
#define S_OFF    1142784
#define F_OFF    1732608
#define QT_OFF   10579968
#define WS_FLOATS 27095040

__device__ __forceinline__ int off_w_f(int s)  { return 49152  * ((1 << s) - 1); }
__device__ __forceinline__ int qoff_f(int s)   { return 2359296 * ((1 << s) - 1); }
__device__ __forceinline__ int ktoff_f(int s)  { return 36864  * ((1 << s) - 1); }
__device__ __forceinline__ int foff_f(int s)   { return 1179648 * ((1 << s) - 1); }

// ---------------------------------------------------------------------------
// Legacy 64x64 tile GEMM (used only by the small doubling-chain kernels).
// ---------------------------------------------------------------------------
template<bool BT>
__device__ __forceinline__ void gemm_tile(const float* __restrict__ A,
                                          const float* __restrict__ B,
                                          float* __restrict__ C,
                                          int M, int N, int ldc, int m0, int n0)
{
    __shared__ float As[16][68];
    __shared__ float Bs[16][68];
    const int tid = threadIdx.x;
    const int tx = tid & 15;
    const int ty = tid >> 4;
    const int r  = tid >> 2;
    const int kq = (tid & 3) << 2;

    float acc[4][4] = {{0.f,0.f,0.f,0.f},{0.f,0.f,0.f,0.f},
                       {0.f,0.f,0.f,0.f},{0.f,0.f,0.f,0.f}};

    for (int kk = 0; kk < 256; kk += 16) {
        float4 av = make_float4(0.f, 0.f, 0.f, 0.f);
        if (m0 + r < M)
            av = *(const float4*)(A + (size_t)(m0 + r) * 256 + kk + kq);
        As[kq + 0][r] = av.x; As[kq + 1][r] = av.y;
        As[kq + 2][r] = av.z; As[kq + 3][r] = av.w;

        if (BT) {
            float4 bv = make_float4(0.f, 0.f, 0.f, 0.f);
            if (n0 + r < N)
                bv = *(const float4*)(B + (size_t)(n0 + r) * 256 + kk + kq);
            Bs[kq + 0][r] = bv.x; Bs[kq + 1][r] = bv.y;
            Bs[kq + 2][r] = bv.z; Bs[kq + 3][r] = bv.w;
        } else {
            const int kb = tid >> 4;
            const int j4 = (tid & 15) << 2;
            float4 bv = *(const float4*)(B + (size_t)(kk + kb) * 256 + n0 + j4);
            *(float4*)(&Bs[kb][j4]) = bv;
        }
        __syncthreads();

        #pragma unroll
        for (int k = 0; k < 16; ++k) {
            float4 a4 = *(const float4*)(&As[k][ty << 2]);
            float4 b4 = *(const float4*)(&Bs[k][tx << 2]);
            acc[0][0] = fmaf(a4.x, b4.x, acc[0][0]);
            acc[0][1] = fmaf(a4.x, b4.y, acc[0][1]);
            acc[0][2] = fmaf(a4.x, b4.z, acc[0][2]);
            acc[0][3] = fmaf(a4.x, b4.w, acc[0][3]);
            acc[1][0] = fmaf(a4.y, b4.x, acc[1][0]);
            acc[1][1] = fmaf(a4.y, b4.y, acc[1][1]);
            acc[1][2] = fmaf(a4.y, b4.z, acc[1][2]);
            acc[1][3] = fmaf(a4.y, b4.w, acc[1][3]);
            acc[2][0] = fmaf(a4.z, b4.x, acc[2][0]);
            acc[2][1] = fmaf(a4.z, b4.y, acc[2][1]);
            acc[2][2] = fmaf(a4.z, b4.z, acc[2][2]);
            acc[2][3] = fmaf(a4.z, b4.w, acc[2][3]);
            acc[3][0] = fmaf(a4.w, b4.x, acc[3][0]);
            acc[3][1] = fmaf(a4.w, b4.y, acc[3][1]);
            acc[3][2] = fmaf(a4.w, b4.z, acc[3][2]);
            acc[3][3] = fmaf(a4.w, b4.w, acc[3][3]);
        }
        __syncthreads();
    }

    #pragma unroll
    for (int u = 0; u < 4; ++u) {
        int row = m0 + (ty << 2) + u;
        if (row < M) {
            float4 cv = make_float4(acc[u][0], acc[u][1], acc[u][2], acc[u][3]);
            *(float4*)(C + (size_t)row * ldc + n0 + (tx << 2)) = cv;
        }
    }
}

// ---------------------------------------------------------------------------
// Q workhorse (r7-proven): C[64][128] = A[64][256] @ B^T, K=256, 256 threads,
// 4x8 microtile, single-buffered.
// ---------------------------------------------------------------------------
__device__ __forceinline__ void gemm64x128_q(const float* __restrict__ A,
                                             const float* __restrict__ B,
                                             float* __restrict__ C, int ldc)
{
    __shared__ float As[16][68];
    __shared__ float Bs[16][132];

    const int tid = threadIdx.x;
    const int tx = tid & 15;
    const int ty = tid >> 4;
    const int ra  = tid >> 2;          // 0..63
    const int kqa = (tid & 3) << 2;    // 0,4,8,12
    const int rb  = tid >> 1;          // 0..127
    const int kq8 = (tid & 1) << 3;    // 0 or 8

    float acc[2][4][4];                // [colgrp g][row u][v]
    #pragma unroll
    for (int g = 0; g < 2; ++g)
        #pragma unroll
        for (int u = 0; u < 4; ++u)
            #pragma unroll
            for (int v = 0; v < 4; ++v) acc[g][u][v] = 0.f;

    for (int kk = 0; kk < 256; kk += 16) {
        float4 av = *(const float4*)(A + (size_t)ra * 256 + kk + kqa);
        As[kqa + 0][ra] = av.x; As[kqa + 1][ra] = av.y;
        As[kqa + 2][ra] = av.z; As[kqa + 3][ra] = av.w;

        const float* bp = B + (size_t)rb * 256 + kk + kq8;
        float4 b0 = *(const float4*)(bp);
        float4 b1 = *(const float4*)(bp + 4);
        Bs[kq8 + 0][rb] = b0.x; Bs[kq8 + 1][rb] = b0.y;
        Bs[kq8 + 2][rb] = b0.z; Bs[kq8 + 3][rb] = b0.w;
        Bs[kq8 + 4][rb] = b1.x; Bs[kq8 + 5][rb] = b1.y;
        Bs[kq8 + 6][rb] = b1.z; Bs[kq8 + 7][rb] = b1.w;
        __syncthreads();

        #pragma unroll
        for (int kq = 0; kq < 16; ++kq) {
            float4 a   = *(const float4*)(&As[kq][4 * ty]);
            float4 b0v = *(const float4*)(&Bs[kq][4 * tx]);
            float4 b1v = *(const float4*)(&Bs[kq][4 * tx + 64]);
            float af[4] = {a.x, a.y, a.z, a.w};
            float bf[8] = {b0v.x, b0v.y, b0v.z, b0v.w, b1v.x, b1v.y, b1v.z, b1v.w};
            #pragma unroll
            for (int g = 0; g < 2; ++g)
                #pragma unroll
                for (int u = 0; u < 4; ++u)
                    #pragma unroll
                    for (int v = 0; v < 4; ++v)
                        acc[g][u][v] = fmaf(af[u], bf[g * 4 + v], acc[g][u][v]);
        }
        __syncthreads();
    }

    #pragma unroll
    for (int u = 0; u < 4; ++u) {
        int row = 4 * ty + u;
        #pragma unroll
        for (int g = 0; g < 2; ++g) {
            float4 cv = make_float4(acc[g][u][0], acc[g][u][1],
                                    acc[g][u][2], acc[g][u][3]);
            *(float4*)(C + (size_t)row * ldc + 4 * tx + 64 * g) = cv;
        }
    }
}

// ---------------------------------------------------------------------------
// Y workhorse (r10-proven): 64x128 tile, 128 threads, 8x8 microtile.
// ---------------------------------------------------------------------------
__device__ __forceinline__ void gemm64x128_y(const float* __restrict__ A,
                                             const float* __restrict__ B,
                                             float* __restrict__ C, int ldc)
{
    __shared__ float As[16][68];
    __shared__ float Bs[16][132];

    const int tid = threadIdx.x;       // 0..127
    const int tx  = tid & 15;
    const int ty  = tid >> 4;          // 0..7
    const int ra  = tid >> 1;          // 0..63
    const int kq8 = (tid & 1) << 3;

    float acc[2][2][4][4];
    #pragma unroll
    for (int h = 0; h < 2; ++h)
        #pragma unroll
        for (int g = 0; g < 2; ++g)
            #pragma unroll
            for (int u = 0; u < 4; ++u)
                #pragma unroll
                for (int v = 0; v < 4; ++v) acc[h][g][u][v] = 0.f;

    for (int kk = 0; kk < 256; kk += 16) {
        const float* ap = A + (size_t)ra * 256 + kk + kq8;
        float4 a0 = *(const float4*)(ap);
        float4 a1 = *(const float4*)(ap + 4);
        As[kq8 + 0][ra] = a0.x; As[kq8 + 1][ra] = a0.y;
        As[kq8 + 2][ra] = a0.z; As[kq8 + 3][ra] = a0.w;
        As[kq8 + 4][ra] = a1.x; As[kq8 + 5][ra] = a1.y;
        As[kq8 + 6][ra] = a1.z; As[kq8 + 7][ra] = a1.w;

        const float* bp = B + (size_t)tid * 256 + kk;
        float4 b0 = *(const float4*)(bp);
        float4 b1 = *(const float4*)(bp + 4);
        float4 b2 = *(const float4*)(bp + 8);
        float4 b3 = *(const float4*)(bp + 12);
        Bs[ 0][tid] = b0.x; Bs[ 1][tid] = b0.y; Bs[ 2][tid] = b0.z; Bs[ 3][tid] = b0.w;
        Bs[ 4][tid] = b1.x; Bs[ 5][tid] = b1.y; Bs[ 6][tid] = b1.z; Bs[ 7][tid] = b1.w;
        Bs[ 8][tid] = b2.x; Bs[ 9][tid] = b2.y; Bs[10][tid] = b2.z; Bs[11][tid] = b2.w;
        Bs[12][tid] = b3.x; Bs[13][tid] = b3.y; Bs[14][tid] = b3.z; Bs[15][tid] = b3.w;
        __syncthreads();

        #pragma unroll
        for (int kq = 0; kq < 16; ++kq) {
            float4 aA = *(const float4*)(&As[kq][4 * ty]);
            float4 aB = *(const float4*)(&As[kq][4 * ty + 32]);
            float4 bA = *(const float4*)(&Bs[kq][4 * tx]);
            float4 bB = *(const float4*)(&Bs[kq][4 * tx + 64]);
            float af[8] = {aA.x, aA.y, aA.z, aA.w, aB.x, aB.y, aB.z, aB.w};
            float bf[8] = {bA.x, bA.y, bA.z, bA.w, bB.x, bB.y, bB.z, bB.w};
            #pragma unroll
            for (int h = 0; h < 2; ++h)
                #pragma unroll
                for (int u = 0; u < 4; ++u)
                    #pragma unroll
                    for (int g = 0; g < 2; ++g)
                        #pragma unroll
                        for (int v = 0; v < 4; ++v)
                            acc[h][g][u][v] = fmaf(af[h * 4 + u], bf[g * 4 + v],
                                                   acc[h][g][u][v]);
        }
        __syncthreads();
    }

    #pragma unroll
    for (int h = 0; h < 2; ++h)
        #pragma unroll
        for (int u = 0; u < 4; ++u) {
            int row = 4 * ty + 32 * h + u;
            #pragma unroll
            for (int g = 0; g < 2; ++g) {
                float4 cv = make_float4(acc[h][g][u][0], acc[h][g][u][1],
                                        acc[h][g][u][2], acc[h][g][u][3]);
                *(float4*)(C + (size_t)row * ldc + 4 * tx + 64 * g) = cv;
            }
        }
}

// ---------------------------------------------------------------------------
__global__ void k_init(const float* B0, const float* B1, const float* B2, float* ws)
{
    int s = blockIdx.x;
    const float* Bv = (s == 0) ? B0 : (s == 1) ? B1 : B2;
    ws[W_OFF + off_w_f(s) + threadIdx.x] = Bv[threadIdx.x];
}

// ---------------------------------------------------------------------------
// doubling level n: jump w[2^n + r] = Apow_n @ w[r]; square Apow_{n+1}
// ---------------------------------------------------------------------------
__global__ void k_level(int n, const float* A0, const float* A1, const float* A2,
                        float* ws)
{
    int s = blockIdx.z;
    int L = 192 << s;
    const float* Ain = (s == 0) ? A0 : (s == 1) ? A1 : A2;
    float* wbase = ws + W_OFF + off_w_f(s);
    float* bufA  = ws + AP_OFF + s * 131072;
    float* bufB  = bufA + 65536;
    const float* src = (n == 0) ? Ain : (((n - 1) & 1) ? bufB : bufA);

    int y = blockIdx.y;
    if (y < 4) {
        int p2 = 1 << n;
        if (p2 >= L) return;
        int cnt = min(p2, L - p2);
        int m0 = y * 64;
        if (m0 >= cnt) return;
        gemm_tile<true>(wbase, src, wbase + (size_t)p2 * 256,
                        cnt, 256, 256, m0, blockIdx.x * 64);
    } else {
        if ((2 << n) >= L) return;
        float* dst = (n & 1) ? bufB : bufA;
        gemm_tile<false>(src, src, dst, 256, 256, 256, (y - 4) * 64, blockIdx.x * 64);
    }
}

// ---------------------------------------------------------------------------
// Wt[s][ri][k][i][o] = W[i][o][k]  — LDS-staged, fully coalesced.
// ---------------------------------------------------------------------------
__global__ void k_transpose(const float* Wr0, const float* Wi0,
                            const float* Wr1, const float* Wi1,
                            const float* Wr2, const float* Wi2, float* ws)
{
    __shared__ float t[256][33];
    int bid = blockIdx.x;
    int i  = bid & 255;
    int ri = (bid >> 8) & 1;
    int s  = bid >> 9;
    const float* W;
    if (s == 0)      W = ri ? Wi0 : Wr0;
    else if (s == 1) W = ri ? Wi1 : Wr1;
    else             W = ri ? Wi2 : Wr2;

    const int tid = threadIdx.x;
    const float* slab = W + (size_t)i * 8192;
    #pragma unroll
    for (int j = 0; j < 8; ++j) {
        int f = j * 1024 + tid * 4;
        float4 v = *(const float4*)(slab + f);
        int o = f >> 5;
        int k = f & 31;
        t[o][k + 0] = v.x; t[o][k + 1] = v.y;
        t[o][k + 2] = v.z; t[o][k + 3] = v.w;
    }
    __syncthreads();

    int sri = s * 2 + ri;
    #pragma unroll
    for (int k = 0; k < 32; ++k) {
        ws[QT_OFF + (size_t)(sri * 32 + k) * 65536 + (size_t)i * 256 + tid] = t[tid][k];
    }
}

// ---------------------------------------------------------------------------
// Y[z][p][i] = sum_o E[L-192+p][o] * Wt[z][i][o]
// grid (128, 3, 3): x = (zz<<1)|ihalf, y = p-tile, z = s.  128 threads.
// ---------------------------------------------------------------------------
__global__ void __launch_bounds__(128, 4)
k_gemm_Y4(const float* E0, const float* E1, const float* E2, float* __restrict__ ws)
{
    const int s  = blockIdx.z;
    const int L  = 192 << s;
    const int zz = blockIdx.x >> 1;              // 0..63
    const int n0 = (blockIdx.x & 1) * 128;       // i half
    const int z  = s * 64 + zz;
    const int m0 = blockIdx.y * 64;              // p tile
    const float* E = (s == 0) ? E0 : (s == 1) ? E1 : E2;

    const float* Ap = E + (size_t)(L - 192) * 256 + (size_t)m0 * 256;
    const float* Bp = ws + QT_OFF + (size_t)z * 65536 + (size_t)n0 * 256;
    float* Cp = ws + Y_OFF + (size_t)z * 49152 + (size_t)m0 * 256 + n0;
    gemm64x128_y(Ap, Bp, Cp, 256);
}

// ---------------------------------------------------------------------------
// Qb[s][d][n] = sum_i w[s][d][i] * Y[n][i],  n = (ri*32+k)*192+p
// Y rows n at Y_OFF + s*3145728 + n*256, i (=K) fastest.
// grid (96, 21): x = 128-col tile of n, y = packed (s, d-tile).  256 threads.
// ---------------------------------------------------------------------------
__global__ void __launch_bounds__(256, 4)
k_gemm_Q4(float* __restrict__ ws)
{
    const int y = blockIdx.y;
    int s, yt;
    if (y < 3)      { s = 0; yt = y; }
    else if (y < 9) { s = 1; yt = y - 3; }
    else            { s = 2; yt = y - 9; }
    const int m0 = yt * 64;
    const int n0 = blockIdx.x * 128;

    const float* Ap = ws + W_OFF + off_w_f(s) + (size_t)m0 * 256;
    const float* Bp = ws + Y_OFF + (size_t)s * 3145728 + (size_t)n0 * 256;
    float* Cp = ws + QT_OFF + qoff_f(s) + (size_t)m0 * 12288 + n0;
    gemm64x128_q(Ap, Bp, Cp, 12288);
}

// ---------------------------------------------------------------------------
// Pass 1 of chunked twiddled scan: complex chunk sums (16 chunks of L/16).
// grid (16, 32, 3), block 192 (= p)
// ---------------------------------------------------------------------------
__global__ void k_scanA(float* __restrict__ ws)
{
    const int c = blockIdx.x;
    const int k = blockIdx.y;
    const int s = blockIdx.z;
    const int L = 192 << s;
    const int C = L >> 4;
    const int p = threadIdx.x;

    __shared__ float twc[768], tws[768];
    for (int m = p; m < L; m += 192) {
        float ang = -2.f * PI_F * (float)m / (float)L;
        float ss, cc; sincosf(ang, &ss, &cc);
        twc[m] = cc; tws[m] = ss;
    }
    __syncthreads();

    const float* Qr = ws + QT_OFF + qoff_f(s) + (size_t)k * 192;
    const float* Qi = Qr + 6144;

    float ar = 0.f, ai = 0.f;
    const int d0 = c * C;
    int ph = (k * d0) % L;
    for (int j = 0; j < C; ++j) {
        int d = d0 + j;
        float qr = Qr[(size_t)d * 12288 + p];
        float qi = Qi[(size_t)d * 12288 + p];
        float cc = twc[ph], sn = tws[ph];
        ar = fmaf(cc, qr, fmaf(-sn, qi, ar));
        ai = fmaf(cc, qi, fmaf( sn, qr, ai));
        ph += k; if (ph >= L) ph -= L;
    }
    size_t sb = (size_t)((s * 32 + k) * 16 + c) * 384;
    ws[S_OFF + sb + p]       = ar;
    ws[S_OFF + sb + 192 + p] = ai;
}

// ---------------------------------------------------------------------------
// Pass 2: offset from chunk sums, rescan own chunk, fold phase into F.
// grid (16, 32, 3), block 192
// ---------------------------------------------------------------------------
__global__ void k_scanB(float* __restrict__ ws)
{
    const int c = blockIdx.x;
    const int k = blockIdx.y;
    const int s = blockIdx.z;
    const int L = 192 << s;
    const int C = L >> 4;
    const int p = threadIdx.x;

    __shared__ float twc[768], tws[768];
    for (int m = p; m < L; m += 192) {
        float ang = -2.f * PI_F * (float)m / (float)L;
        float ss, cc; sincosf(ang, &ss, &cc);
        twc[m] = cc; tws[m] = ss;
    }
    __syncthreads();

    float ar = 0.f, ai = 0.f;
    size_t sbase = (size_t)(s * 32 + k) * 16 * 384;
    for (int c2 = 0; c2 < c; ++c2) {
        ar += ws[S_OFF + sbase + (size_t)c2 * 384 + p];
        ai += ws[S_OFF + sbase + (size_t)c2 * 384 + 192 + p];
    }

    const float ck = ((k == 0) ? 1.f : 2.f) / (float)L;
    const float* Qr = ws + QT_OFF + qoff_f(s) + (size_t)k * 192;
    const float* Qi = Qr + 6144;
    float* F = ws + F_OFF + foff_f(s);

    const int d0 = c * C;
    int ph = (k * d0) % L;
    int m1 = d0 + 192 - L; if (m1 < 0) m1 += L;
    int ph2 = (k * m1) % L;
    for (int j = 0; j < C; ++j) {
        int d = d0 + j;
        float qr = Qr[(size_t)d * 12288 + p];
        float qi = Qi[(size_t)d * 12288 + p];
        float cc = twc[ph], sn = tws[ph];
        ar = fmaf(cc, qr, fmaf(-sn, qi, ar));
        ai = fmaf(cc, qi, fmaf( sn, qr, ai));
        float f = ck * fmaf(twc[ph2], ar, tws[ph2] * ai);
        int sidx = L - 1 - d;
        F[((size_t)sidx * 32 + k) * 192 + p] = f;
        ph  += k; if (ph  >= L) ph  -= L;
        ph2 += k; if (ph2 >= L) ph2 -= L;
    }
}

// ---------------------------------------------------------------------------
// Ktil[s][sidx][p] = sum_k F[s][sidx][k][p]
// ---------------------------------------------------------------------------
__global__ void k_kred(float* __restrict__ ws)
{
    int bid = blockIdx.x;
    int s, sidx;
    if (bid < 192)      { s = 0; sidx = bid; }
    else if (bid < 576) { s = 1; sidx = bid - 192; }
    else                { s = 2; sidx = bid - 576; }
    int p = threadIdx.x;
    const float* F = ws + F_OFF + foff_f(s) + (size_t)sidx * 32 * 192;
    float sum = 0.f;
    #pragma unroll
    for (int k = 0; k < 32; ++k)
        sum += F[k * 192 + p];
    ws[KT_OFF + ktoff_f(s) + (size_t)sidx * 192 + p] = sum;
}

// ---------------------------------------------------------------------------
__global__ void k_combine(float* ws, const float* mw)
{
    int idx = blockIdx.x * 256 + threadIdx.x;
    if (idx >= 147456) return;
    int tau = idx / 192;
    int p   = idx - tau * 192;
    float sum = 0.f;
    #pragma unroll
    for (int s = 0; s < 3; ++s) {
        int L = 192 << s;
        int off = 768 - L;
        if (tau >= off)
            sum = fmaf(mw[s], ws[KT_OFF + ktoff_f(s) + (size_t)(tau - off) * 192 + p], sum);
    }
    ws[KTOT_OFF + idx] = sum;
}

// ---------------------------------------------------------------------------
__global__ void k_out(const float* __restrict__ x, const float* __restrict__ ws,
                      const float* __restrict__ mb, float* __restrict__ out)
{
    int bid = blockIdx.x;
    int b = bid / 21;
    int c = bid - b * 21;
    __shared__ float xl[768];
    for (int t = threadIdx.x; t < 768; t += 192)
        xl[t] = x[((size_t)b * 768 + t) * 21 + c];
    __syncthreads();

    int p = threadIdx.x;
    const float* K = ws + KTOT_OFF;
    float acc = 0.f;
    for (int tau = 0; tau < 768; ++tau)
        acc = fmaf(xl[tau], K[(size_t)tau * 192 + p], acc);
    out[((size_t)b * 192 + p) * 21 + c] = acc + mb[0];
}

// ---------------------------------------------------------------------------
extern "C" void kernel_launch(void* const* d_in, const int* in_sizes, int n_in,
                              void* d_out, int out_size, void* d_ws, size_t ws_size,
                              hipStream_t stream)
{
    const float* x   = (const float*)d_in[0];
    const float* A0  = (const float*)d_in[1];
    const float* B0  = (const float*)d_in[2];
    const float* E0  = (const float*)d_in[3];
    const float* Wr0 = (const float*)d_in[4];
    const float* Wi0 = (const float*)d_in[5];
    const float* A1  = (const float*)d_in[6];
    const float* B1  = (const float*)d_in[7];
    const float* E1  = (const float*)d_in[8];
    const float* Wr1 = (const float*)d_in[9];
    const float* Wi1 = (const float*)d_in[10];
    const float* A2  = (const float*)d_in[11];
    const float* B2  = (const float*)d_in[12];
    const float* E2  = (const float*)d_in[13];
    const float* Wr2 = (const float*)d_in[14];
    const float* Wi2 = (const float*)d_in[15];
    const float* mw  = (const float*)d_in[16];
    const float* mb  = (const float*)d_in[17];
    float* ws  = (float*)d_ws;
    float* out = (float*)d_out;

    if (ws_size < (size_t)WS_FLOATS * sizeof(float)) {
        hipMemsetAsync(d_out, 0, (size_t)out_size * sizeof(float), stream);
        return;
    }

    k_init<<<3, 256, 0, stream>>>(B0, B1, B2, ws);
    for (int n = 0; n < 10; ++n)
        k_level<<<dim3(4, 8, 3), 256, 0, stream>>>(n, A0, A1, A2, ws);
    k_transpose<<<1536, 256, 0, stream>>>(Wr0, Wi0, Wr1, Wi1, Wr2, Wi2, ws);
    k_gemm_Y4<<<dim3(128, 3, 3), 128, 0, stream>>>(E0, E1, E2, ws);
    k_gemm_Q4<<<dim3(96, 21), 256, 0, stream>>>(ws);
    k_scanA<<<dim3(16, 32, 3), 192, 0, stream>>>(ws);
    k_scanB<<<dim3(16, 32, 3), 192, 0, stream>>>(ws);
    k_kred<<<1344, 192, 0, stream>>>(ws);
    k_combine<<<576, 256, 0, stream>>>(ws, mw);
    k_out<<<336, 192, 0, stream>>>(x, ws, mb, out);
}

// Round 15
// 421.703 us; speedup vs baseline: 1.7663x; 1.0209x over previous
//
#include <hip/hip_runtime.h>
#include <math.h>

#define PI_F 3.14159265358979323846f

// ---------------------------------------------------------------------------
// N_ORDER=256, PRED_LEN=192, SEQ_LEN=768, ENC_IN=21, B=16, L_s=192<<s, MODES=32
//
// Pipeline (all linear in x; kernel-matrix construction then one apply):
//   w_d = A^d B                      (doubling chain, 10 levels)
//   Wt[(s,ri,k)][i][o] = W[i][o][k]  (transpose, LDS-staged)
//   Y[z][p][i] = sum_o Wt[z][i][o] E[L-192+p][o]           (GEMM, 4.8 GF)
//   Qb[s][d][n] = sum_i w_d[i] Y[n][i],  n=(ri,k,p)        (GEMM, 8.5 GF)
//   Z[k][d][p] = sum_{d'<=d} e^{-2pi i k d'/L} Q[k][d'][p] (chunked scan)
//   F[s][sidx][k][p] = c_k Re(e^{2pi i k((191-sidx)%L)/L} Z[k][L-1-sidx][p])
//   Ktot[tau][p] = sum_s mlp_w[s] * sum_k F[s][tau-(768-L_s)][k][p]  (fused)
//   out[b][p][c] = sum_tau x[b][tau][c] Ktot[tau][p] + mlp_b
//
// Workspace layout (float offsets):
//   w    [s][d][i]        : 0        len 344064
//   Apow [s][2][65536]    : 344064   len 393216
//   Ktil (unused now)     : 737280   len 258048
//   Ktot [tau][p]         : 995328   len 147456
//   Y    [z][p][i]        : 1142784  len 9437184   (dead after k_gemm_Q4;
//        S (chunk sums)   : 1142784  len 589824     reused by scan)
//        F (folded)       : 1732608  len 8257536
//   QT region (time-shared):
//     Wt [z][i][o]        : 10579968 len 12582912
//     Qb [s][d][12288]    : 10579968 len 16515072
// Total 27,095,040 floats (proven to fit)
// ---------------------------------------------------------------------------
#define W_OFF    0
#define AP_OFF   344064
#define KT_OFF   737280
#define KTOT_OFF 995328
#define Y_OFF    1142784
#define S_OFF    1142784
#define F_OFF    1732608
#define QT_OFF   10579968
#define WS_FLOATS 27095040

__device__ __forceinline__ int off_w_f(int s)  { return 49152  * ((1 << s) - 1); }
__device__ __forceinline__ int qoff_f(int s)   { return 2359296 * ((1 << s) - 1); }
__device__ __forceinline__ int foff_f(int s)   { return 1179648 * ((1 << s) - 1); }

// ---------------------------------------------------------------------------
// Legacy 64x64 tile GEMM (used only by the small doubling-chain kernels).
// ---------------------------------------------------------------------------
template<bool BT>
__device__ __forceinline__ void gemm_tile(const float* __restrict__ A,
                                          const float* __restrict__ B,
                                          float* __restrict__ C,
                                          int M, int N, int ldc, int m0, int n0)
{
    __shared__ float As[16][68];
    __shared__ float Bs[16][68];
    const int tid = threadIdx.x;
    const int tx = tid & 15;
    const int ty = tid >> 4;
    const int r  = tid >> 2;
    const int kq = (tid & 3) << 2;

    float acc[4][4] = {{0.f,0.f,0.f,0.f},{0.f,0.f,0.f,0.f},
                       {0.f,0.f,0.f,0.f},{0.f,0.f,0.f,0.f}};

    for (int kk = 0; kk < 256; kk += 16) {
        float4 av = make_float4(0.f, 0.f, 0.f, 0.f);
        if (m0 + r < M)
            av = *(const float4*)(A + (size_t)(m0 + r) * 256 + kk + kq);
        As[kq + 0][r] = av.x; As[kq + 1][r] = av.y;
        As[kq + 2][r] = av.z; As[kq + 3][r] = av.w;

        if (BT) {
            float4 bv = make_float4(0.f, 0.f, 0.f, 0.f);
            if (n0 + r < N)
                bv = *(const float4*)(B + (size_t)(n0 + r) * 256 + kk + kq);
            Bs[kq + 0][r] = bv.x; Bs[kq + 1][r] = bv.y;
            Bs[kq + 2][r] = bv.z; Bs[kq + 3][r] = bv.w;
        } else {
            const int kb = tid >> 4;
            const int j4 = (tid & 15) << 2;
            float4 bv = *(const float4*)(B + (size_t)(kk + kb) * 256 + n0 + j4);
            *(float4*)(&Bs[kb][j4]) = bv;
        }
        __syncthreads();

        #pragma unroll
        for (int k = 0; k < 16; ++k) {
            float4 a4 = *(const float4*)(&As[k][ty << 2]);
            float4 b4 = *(const float4*)(&Bs[k][tx << 2]);
            acc[0][0] = fmaf(a4.x, b4.x, acc[0][0]);
            acc[0][1] = fmaf(a4.x, b4.y, acc[0][1]);
            acc[0][2] = fmaf(a4.x, b4.z, acc[0][2]);
            acc[0][3] = fmaf(a4.x, b4.w, acc[0][3]);
            acc[1][0] = fmaf(a4.y, b4.x, acc[1][0]);
            acc[1][1] = fmaf(a4.y, b4.y, acc[1][1]);
            acc[1][2] = fmaf(a4.y, b4.z, acc[1][2]);
            acc[1][3] = fmaf(a4.y, b4.w, acc[1][3]);
            acc[2][0] = fmaf(a4.z, b4.x, acc[2][0]);
            acc[2][1] = fmaf(a4.z, b4.y, acc[2][1]);
            acc[2][2] = fmaf(a4.z, b4.z, acc[2][2]);
            acc[2][3] = fmaf(a4.z, b4.w, acc[2][3]);
            acc[3][0] = fmaf(a4.w, b4.x, acc[3][0]);
            acc[3][1] = fmaf(a4.w, b4.y, acc[3][1]);
            acc[3][2] = fmaf(a4.w, b4.z, acc[3][2]);
            acc[3][3] = fmaf(a4.w, b4.w, acc[3][3]);
        }
        __syncthreads();
    }

    #pragma unroll
    for (int u = 0; u < 4; ++u) {
        int row = m0 + (ty << 2) + u;
        if (row < M) {
            float4 cv = make_float4(acc[u][0], acc[u][1], acc[u][2], acc[u][3]);
            *(float4*)(C + (size_t)row * ldc + n0 + (tx << 2)) = cv;
        }
    }
}

// ---------------------------------------------------------------------------
// Workhorse (r7-proven): C[64][128] = A[64][256] @ B^T, K=256, 256 threads,
// 4x8 microtile, single-buffered.  A pre-offset to (m0,0), stride 256, K
// fastest.  B rows are output cols (pre-offset n0), stride 256, K fastest.
// ---------------------------------------------------------------------------
__device__ __forceinline__ void gemm64x128_q(const float* __restrict__ A,
                                             const float* __restrict__ B,
                                             float* __restrict__ C, int ldc)
{
    __shared__ float As[16][68];
    __shared__ float Bs[16][132];

    const int tid = threadIdx.x;
    const int tx = tid & 15;
    const int ty = tid >> 4;
    const int ra  = tid >> 2;          // 0..63
    const int kqa = (tid & 3) << 2;    // 0,4,8,12
    const int rb  = tid >> 1;          // 0..127
    const int kq8 = (tid & 1) << 3;    // 0 or 8

    float acc[2][4][4];                // [colgrp g][row u][v]
    #pragma unroll
    for (int g = 0; g < 2; ++g)
        #pragma unroll
        for (int u = 0; u < 4; ++u)
            #pragma unroll
            for (int v = 0; v < 4; ++v) acc[g][u][v] = 0.f;

    for (int kk = 0; kk < 256; kk += 16) {
        float4 av = *(const float4*)(A + (size_t)ra * 256 + kk + kqa);
        As[kqa + 0][ra] = av.x; As[kqa + 1][ra] = av.y;
        As[kqa + 2][ra] = av.z; As[kqa + 3][ra] = av.w;

        const float* bp = B + (size_t)rb * 256 + kk + kq8;
        float4 b0 = *(const float4*)(bp);
        float4 b1 = *(const float4*)(bp + 4);
        Bs[kq8 + 0][rb] = b0.x; Bs[kq8 + 1][rb] = b0.y;
        Bs[kq8 + 2][rb] = b0.z; Bs[kq8 + 3][rb] = b0.w;
        Bs[kq8 + 4][rb] = b1.x; Bs[kq8 + 5][rb] = b1.y;
        Bs[kq8 + 6][rb] = b1.z; Bs[kq8 + 7][rb] = b1.w;
        __syncthreads();

        #pragma unroll
        for (int kq = 0; kq < 16; ++kq) {
            float4 a   = *(const float4*)(&As[kq][4 * ty]);
            float4 b0v = *(const float4*)(&Bs[kq][4 * tx]);
            float4 b1v = *(const float4*)(&Bs[kq][4 * tx + 64]);
            float af[4] = {a.x, a.y, a.z, a.w};
            float bf[8] = {b0v.x, b0v.y, b0v.z, b0v.w, b1v.x, b1v.y, b1v.z, b1v.w};
            #pragma unroll
            for (int g = 0; g < 2; ++g)
                #pragma unroll
                for (int u = 0; u < 4; ++u)
                    #pragma unroll
                    for (int v = 0; v < 4; ++v)
                        acc[g][u][v] = fmaf(af[u], bf[g * 4 + v], acc[g][u][v]);
        }
        __syncthreads();
    }

    #pragma unroll
    for (int u = 0; u < 4; ++u) {
        int row = 4 * ty + u;
        #pragma unroll
        for (int g = 0; g < 2; ++g) {
            float4 cv = make_float4(acc[g][u][0], acc[g][u][1],
                                    acc[g][u][2], acc[g][u][3]);
            *(float4*)(C + (size_t)row * ldc + 4 * tx + 64 * g) = cv;
        }
    }
}

// ---------------------------------------------------------------------------
__global__ void k_init(const float* B0, const float* B1, const float* B2, float* ws)
{
    int s = blockIdx.x;
    const float* Bv = (s == 0) ? B0 : (s == 1) ? B1 : B2;
    ws[W_OFF + off_w_f(s) + threadIdx.x] = Bv[threadIdx.x];
}

// ---------------------------------------------------------------------------
// doubling level n: jump w[2^n + r] = Apow_n @ w[r]; square Apow_{n+1}
// sbase: z-offset into scale index.
//   n in [0,8): sbase=0, z=3 (all scales)
//   n == 8    : sbase=1, z=2 (s=1 jump cnt=128; s=2 jump+square)
//   n == 9    : sbase=2, z=1 (s=2 jump only)
// ---------------------------------------------------------------------------
__global__ void k_level(int n, int sbase, const float* A0, const float* A1,
                        const float* A2, float* ws)
{
    int s = blockIdx.z + sbase;
    int L = 192 << s;
    const float* Ain = (s == 0) ? A0 : (s == 1) ? A1 : A2;
    float* wbase = ws + W_OFF + off_w_f(s);
    float* bufA  = ws + AP_OFF + s * 131072;
    float* bufB  = bufA + 65536;
    const float* src = (n == 0) ? Ain : (((n - 1) & 1) ? bufB : bufA);

    int y = blockIdx.y;
    if (y < 4) {
        int p2 = 1 << n;
        if (p2 >= L) return;
        int cnt = min(p2, L - p2);
        int m0 = y * 64;
        if (m0 >= cnt) return;
        gemm_tile<true>(wbase, src, wbase + (size_t)p2 * 256,
                        cnt, 256, 256, m0, blockIdx.x * 64);
    } else {
        if ((2 << n) >= L) return;
        float* dst = (n & 1) ? bufB : bufA;
        gemm_tile<false>(src, src, dst, 256, 256, 256, (y - 4) * 64, blockIdx.x * 64);
    }
}

// ---------------------------------------------------------------------------
// Wt[s][ri][k][i][o] = W[i][o][k]  — LDS-staged, fully coalesced.
// ---------------------------------------------------------------------------
__global__ void k_transpose(const float* Wr0, const float* Wi0,
                            const float* Wr1, const float* Wi1,
                            const float* Wr2, const float* Wi2, float* ws)
{
    __shared__ float t[256][33];
    int bid = blockIdx.x;
    int i  = bid & 255;
    int ri = (bid >> 8) & 1;
    int s  = bid >> 9;
    const float* W;
    if (s == 0)      W = ri ? Wi0 : Wr0;
    else if (s == 1) W = ri ? Wi1 : Wr1;
    else             W = ri ? Wi2 : Wr2;

    const int tid = threadIdx.x;
    const float* slab = W + (size_t)i * 8192;
    #pragma unroll
    for (int j = 0; j < 8; ++j) {
        int f = j * 1024 + tid * 4;
        float4 v = *(const float4*)(slab + f);
        int o = f >> 5;
        int k = f & 31;
        t[o][k + 0] = v.x; t[o][k + 1] = v.y;
        t[o][k + 2] = v.z; t[o][k + 3] = v.w;
    }
    __syncthreads();

    int sri = s * 2 + ri;
    #pragma unroll
    for (int k = 0; k < 32; ++k) {
        ws[QT_OFF + (size_t)(sri * 32 + k) * 65536 + (size_t)i * 256 + tid] = t[tid][k];
    }
}

// ---------------------------------------------------------------------------
// Y[z][p][i] = sum_o E[L-192+p][o] * Wt[z][i][o]
// grid (2, 3, 192): x = i-half (128 cols), y = p-tile, z = (s,ri,k).
// Uses the measured-best 256-thread q-tile (same per-element fmaf order).
// ---------------------------------------------------------------------------
__global__ void __launch_bounds__(256, 4)
k_gemm_Y5(const float* E0, const float* E1, const float* E2, float* __restrict__ ws)
{
    const int z  = blockIdx.z;                   // (s,ri,k)
    const int s  = z >> 6;
    const int L  = 192 << s;
    const int n0 = blockIdx.x * 128;             // i half
    const int m0 = blockIdx.y * 64;              // p tile
    const float* E = (s == 0) ? E0 : (s == 1) ? E1 : E2;

    const float* Ap = E + (size_t)(L - 192) * 256 + (size_t)m0 * 256;
    const float* Bp = ws + QT_OFF + (size_t)z * 65536 + (size_t)n0 * 256;
    float* Cp = ws + Y_OFF + (size_t)z * 49152 + (size_t)m0 * 256 + n0;
    gemm64x128_q(Ap, Bp, Cp, 256);
}

// ---------------------------------------------------------------------------
// Qb[s][d][n] = sum_i w[s][d][i] * Y[n][i],  n = (ri*32+k)*192+p
// Y rows n at Y_OFF + s*3145728 + n*256, i (=K) fastest.
// grid (96, 21): x = 128-col tile of n, y = packed (s, d-tile).  256 threads.
// ---------------------------------------------------------------------------
__global__ void __launch_bounds__(256, 4)
k_gemm_Q4(float* __restrict__ ws)
{
    const int y = blockIdx.y;
    int s, yt;
    if (y < 3)      { s = 0; yt = y; }
    else if (y < 9) { s = 1; yt = y - 3; }
    else            { s = 2; yt = y - 9; }
    const int m0 = yt * 64;
    const int n0 = blockIdx.x * 128;

    const float* Ap = ws + W_OFF + off_w_f(s) + (size_t)m0 * 256;
    const float* Bp = ws + Y_OFF + (size_t)s * 3145728 + (size_t)n0 * 256;
    float* Cp = ws + QT_OFF + qoff_f(s) + (size_t)m0 * 12288 + n0;
    gemm64x128_q(Ap, Bp, Cp, 12288);
}

// ---------------------------------------------------------------------------
// Pass 1 of chunked twiddled scan: complex chunk sums (16 chunks of L/16).
// grid (16, 32, 3), block 192 (= p)
// ---------------------------------------------------------------------------
__global__ void k_scanA(float* __restrict__ ws)
{
    const int c = blockIdx.x;
    const int k = blockIdx.y;
    const int s = blockIdx.z;
    const int L = 192 << s;
    const int C = L >> 4;
    const int p = threadIdx.x;

    __shared__ float twc[768], tws[768];
    for (int m = p; m < L; m += 192) {
        float ang = -2.f * PI_F * (float)m / (float)L;
        float ss, cc; sincosf(ang, &ss, &cc);
        twc[m] = cc; tws[m] = ss;
    }
    __syncthreads();

    const float* Qr = ws + QT_OFF + qoff_f(s) + (size_t)k * 192;
    const float* Qi = Qr + 6144;

    float ar = 0.f, ai = 0.f;
    const int d0 = c * C;
    int ph = (k * d0) % L;
    for (int j = 0; j < C; ++j) {
        int d = d0 + j;
        float qr = Qr[(size_t)d * 12288 + p];
        float qi = Qi[(size_t)d * 12288 + p];
        float cc = twc[ph], sn = tws[ph];
        ar = fmaf(cc, qr, fmaf(-sn, qi, ar));
        ai = fmaf(cc, qi, fmaf( sn, qr, ai));
        ph += k; if (ph >= L) ph -= L;
    }
    size_t sb = (size_t)((s * 32 + k) * 16 + c) * 384;
    ws[S_OFF + sb + p]       = ar;
    ws[S_OFF + sb + 192 + p] = ai;
}

// ---------------------------------------------------------------------------
// Pass 2: offset from chunk sums, rescan own chunk, fold phase into F.
// grid (16, 32, 3), block 192
// ---------------------------------------------------------------------------
__global__ void k_scanB(float* __restrict__ ws)
{
    const int c = blockIdx.x;
    const int k = blockIdx.y;
    const int s = blockIdx.z;
    const int L = 192 << s;
    const int C = L >> 4;
    const int p = threadIdx.x;

    __shared__ float twc[768], tws[768];
    for (int m = p; m < L; m += 192) {
        float ang = -2.f * PI_F * (float)m / (float)L;
        float ss, cc; sincosf(ang, &ss, &cc);
        twc[m] = cc; tws[m] = ss;
    }
    __syncthreads();

    float ar = 0.f, ai = 0.f;
    size_t sbase = (size_t)(s * 32 + k) * 16 * 384;
    for (int c2 = 0; c2 < c; ++c2) {
        ar += ws[S_OFF + sbase + (size_t)c2 * 384 + p];
        ai += ws[S_OFF + sbase + (size_t)c2 * 384 + 192 + p];
    }

    const float ck = ((k == 0) ? 1.f : 2.f) / (float)L;
    const float* Qr = ws + QT_OFF + qoff_f(s) + (size_t)k * 192;
    const float* Qi = Qr + 6144;
    float* F = ws + F_OFF + foff_f(s);

    const int d0 = c * C;
    int ph = (k * d0) % L;
    int m1 = d0 + 192 - L; if (m1 < 0) m1 += L;
    int ph2 = (k * m1) % L;
    for (int j = 0; j < C; ++j) {
        int d = d0 + j;
        float qr = Qr[(size_t)d * 12288 + p];
        float qi = Qi[(size_t)d * 12288 + p];
        float cc = twc[ph], sn = tws[ph];
        ar = fmaf(cc, qr, fmaf(-sn, qi, ar));
        ai = fmaf(cc, qi, fmaf( sn, qr, ai));
        float f = ck * fmaf(twc[ph2], ar, tws[ph2] * ai);
        int sidx = L - 1 - d;
        F[((size_t)sidx * 32 + k) * 192 + p] = f;
        ph  += k; if (ph  >= L) ph  -= L;
        ph2 += k; if (ph2 >= L) ph2 -= L;
    }
}

// ---------------------------------------------------------------------------
// Fused k-reduction + scale-combine (arithmetic identical to kred+combine):
//   Ktot[tau][p] = sum_s (tau >= 768-L_s) mlp_w[s] * sum_k F[s][tau-(768-L_s)][k][p]
// grid (768), block 192
// ---------------------------------------------------------------------------
__global__ void k_kredc(float* __restrict__ ws, const float* __restrict__ mw)
{
    const int tau = blockIdx.x;
    const int p   = threadIdx.x;
    float sum = 0.f;
    #pragma unroll
    for (int s = 0; s < 3; ++s) {
        int L = 192 << s;
        int off = 768 - L;
        if (tau >= off) {
            int sidx = tau - off;
            const float* F = ws + F_OFF + foff_f(s) + (size_t)sidx * 32 * 192;
            float kt = 0.f;
            #pragma unroll
            for (int k = 0; k < 32; ++k)
                kt += F[k * 192 + p];
            sum = fmaf(mw[s], kt, sum);
        }
    }
    ws[KTOT_OFF + (size_t)tau * 192 + p] = sum;
}

// ---------------------------------------------------------------------------
__global__ void k_out(const float* __restrict__ x, const float* __restrict__ ws,
                      const float* __restrict__ mb, float* __restrict__ out)
{
    int bid = blockIdx.x;
    int b = bid / 21;
    int c = bid - b * 21;
    __shared__ float xl[768];
    for (int t = threadIdx.x; t < 768; t += 192)
        xl[t] = x[((size_t)b * 768 + t) * 21 + c];
    __syncthreads();

    int p = threadIdx.x;
    const float* K = ws + KTOT_OFF;
    float acc = 0.f;
    for (int tau = 0; tau < 768; ++tau)
        acc = fmaf(xl[tau], K[(size_t)tau * 192 + p], acc);
    out[((size_t)b * 192 + p) * 21 + c] = acc + mb[0];
}

// ---------------------------------------------------------------------------
extern "C" void kernel_launch(void* const* d_in, const int* in_sizes, int n_in,
                              void* d_out, int out_size, void* d_ws, size_t ws_size,
                              hipStream_t stream)
{
    const float* x   = (const float*)d_in[0];
    const float* A0  = (const float*)d_in[1];
    const float* B0  = (const float*)d_in[2];
    const float* E0  = (const float*)d_in[3];
    const float* Wr0 = (const float*)d_in[4];
    const float* Wi0 = (const float*)d_in[5];
    const float* A1  = (const float*)d_in[6];
    const float* B1  = (const float*)d_in[7];
    const float* E1  = (const float*)d_in[8];
    const float* Wr1 = (const float*)d_in[9];
    const float* Wi1 = (const float*)d_in[10];
    const float* A2  = (const float*)d_in[11];
    const float* B2  = (const float*)d_in[12];
    const float* E2  = (const float*)d_in[13];
    const float* Wr2 = (const float*)d_in[14];
    const float* Wi2 = (const float*)d_in[15];
    const float* mw  = (const float*)d_in[16];
    const float* mb  = (const float*)d_in[17];
    float* ws  = (float*)d_ws;
    float* out = (float*)d_out;

    if (ws_size < (size_t)WS_FLOATS * sizeof(float)) {
        hipMemsetAsync(d_out, 0, (size_t)out_size * sizeof(float), stream);
        return;
    }

    k_init<<<3, 256, 0, stream>>>(B0, B1, B2, ws);
    for (int n = 0; n < 8; ++n)
        k_level<<<dim3(4, 8, 3), 256, 0, stream>>>(n, 0, A0, A1, A2, ws);
    k_level<<<dim3(4, 8, 2), 256, 0, stream>>>(8, 1, A0, A1, A2, ws);   // s=1 (jump 128 rows), s=2
    k_level<<<dim3(4, 8, 1), 256, 0, stream>>>(9, 2, A0, A1, A2, ws);   // s=2 only
    k_transpose<<<1536, 256, 0, stream>>>(Wr0, Wi0, Wr1, Wi1, Wr2, Wi2, ws);
    k_gemm_Y5<<<dim3(2, 3, 192), 256, 0, stream>>>(E0, E1, E2, ws);
    k_gemm_Q4<<<dim3(96, 21), 256, 0, stream>>>(ws);
    k_scanA<<<dim3(16, 32, 3), 192, 0, stream>>>(ws);
    k_scanB<<<dim3(16, 32, 3), 192, 0, stream>>>(ws);
    k_kredc<<<768, 192, 0, stream>>>(ws, mw);
    k_out<<<336, 192, 0, stream>>>(x, ws, mb, out);
}

// Round 16
// 400.354 us; speedup vs baseline: 1.8605x; 1.0533x over previous
//
#include <hip/hip_runtime.h>
#include <math.h>

#define PI_F 3.14159265358979323846f

// ---------------------------------------------------------------------------
// N_ORDER=256, PRED_LEN=192, SEQ_LEN=768, ENC_IN=21, B=16, L_s=192<<s, MODES=32
//
// Pipeline (all linear in x; kernel-matrix construction then one apply):
//   w_d = A^d B                      (doubling chain, 10 levels, 32x64 tiles)
//   Wt[(s,ri,k)][i][o] = W[i][o][k]  (transpose, LDS-staged)
//   Y[z][p][i] = sum_o Wt[z][i][o] E[L-192+p][o]           (GEMM, 4.8 GF)
//   Qb[s][d][n] = sum_i w_d[i] Y[n][i],  n=(ri,k,p)        (GEMM, 8.5 GF)
//   Z[k][d][p] = sum_{d'<=d} e^{-2pi i k d'/L} Q[k][d'][p] (chunked scan)
//   F[s][sidx][k][p] = c_k Re(e^{2pi i k((191-sidx)%L)/L} Z[k][L-1-sidx][p])
//   Ktot[tau][p] = sum_s mlp_w[s] * sum_k F[s][tau-(768-L_s)][k][p]  (fused)
//   out[b][p][c] = sum_tau x[b][tau][c] Ktot[tau][p] + mlp_b
//
// Workspace layout (float offsets):
//   w    [s][d][i]        : 0        len 344064
//   Apow [s][2][65536]    : 344064   len 393216
//   Ktil (unused now)     : 737280   len 258048
//   Ktot [tau][p]         : 995328   len 147456
//   Y    [z][p][i]        : 1142784  len 9437184   (dead after k_gemm_Q4;
//        S (chunk sums)   : 1142784  len 589824     reused by scan)
//        F (folded)       : 1732608  len 8257536
//   QT region (time-shared):
//     Wt [z][i][o]        : 10579968 len 12582912
//     Qb [s][d][12288]    : 10579968 len 16515072
// Total 27,095,040 floats (proven to fit)
// ---------------------------------------------------------------------------
#define W_OFF    0
#define AP_OFF   344064
#define KT_OFF   737280
#define KTOT_OFF 995328
#define Y_OFF    1142784
#define S_OFF    1142784
#define F_OFF    1732608
#define QT_OFF   10579968
#define WS_FLOATS 27095040

__device__ __forceinline__ int off_w_f(int s)  { return 49152  * ((1 << s) - 1); }
__device__ __forceinline__ int qoff_f(int s)   { return 2359296 * ((1 << s) - 1); }
__device__ __forceinline__ int foff_f(int s)   { return 1179648 * ((1 << s) - 1); }

// ---------------------------------------------------------------------------
// Chain tile: C[32x64 tile at (m0,n0)] = A[M x 256] @ op(B[256 x 256]),
// 256 threads, 2x4 microtile.  Per-element fmaf chain over k ascending in
// 16-chunks — bitwise-identical to the legacy 64x64 tile.
// BT=true: C = A @ B^T (B row-major, K fastest).  BT=false: C = A @ B.
// ---------------------------------------------------------------------------
template<bool BT>
__device__ __forceinline__ void gemm_tile32(const float* __restrict__ A,
                                            const float* __restrict__ B,
                                            float* __restrict__ C,
                                            int M, int ldc, int m0, int n0)
{
    __shared__ float As[16][36];
    __shared__ float Bs[16][68];
    const int tid = threadIdx.x;
    const int tx = tid & 15;       // 4-col group
    const int ty = tid >> 4;       // 0..15, 2-row group

    float acc[2][4] = {{0.f,0.f,0.f,0.f},{0.f,0.f,0.f,0.f}};

    for (int kk = 0; kk < 256; kk += 16) {
        if (tid < 128) {
            int r  = tid >> 2;             // 0..31
            int kq = (tid & 3) << 2;
            float4 av = make_float4(0.f, 0.f, 0.f, 0.f);
            if (m0 + r < M)
                av = *(const float4*)(A + (size_t)(m0 + r) * 256 + kk + kq);
            As[kq + 0][r] = av.x; As[kq + 1][r] = av.y;
            As[kq + 2][r] = av.z; As[kq + 3][r] = av.w;
        }
        if (BT) {
            int rb = tid >> 2;             // 0..63 (output col)
            int kq = (tid & 3) << 2;
            float4 bv = *(const float4*)(B + (size_t)(n0 + rb) * 256 + kk + kq);
            Bs[kq + 0][rb] = bv.x; Bs[kq + 1][rb] = bv.y;
            Bs[kq + 2][rb] = bv.z; Bs[kq + 3][rb] = bv.w;
        } else {
            int kb = tid >> 4;             // 0..15
            int j4 = (tid & 15) << 2;
            float4 bv = *(const float4*)(B + (size_t)(kk + kb) * 256 + n0 + j4);
            *(float4*)(&Bs[kb][j4]) = bv;
        }
        __syncthreads();

        #pragma unroll
        for (int kq = 0; kq < 16; ++kq) {
            float a0 = As[kq][2 * ty];
            float a1 = As[kq][2 * ty + 1];
            float4 b4 = *(const float4*)(&Bs[kq][tx << 2]);
            acc[0][0] = fmaf(a0, b4.x, acc[0][0]);
            acc[0][1] = fmaf(a0, b4.y, acc[0][1]);
            acc[0][2] = fmaf(a0, b4.z, acc[0][2]);
            acc[0][3] = fmaf(a0, b4.w, acc[0][3]);
            acc[1][0] = fmaf(a1, b4.x, acc[1][0]);
            acc[1][1] = fmaf(a1, b4.y, acc[1][1]);
            acc[1][2] = fmaf(a1, b4.z, acc[1][2]);
            acc[1][3] = fmaf(a1, b4.w, acc[1][3]);
        }
        __syncthreads();
    }

    #pragma unroll
    for (int u = 0; u < 2; ++u) {
        int row = m0 + 2 * ty + u;
        if (row < M) {
            float4 cv = make_float4(acc[u][0], acc[u][1], acc[u][2], acc[u][3]);
            *(float4*)(C + (size_t)row * ldc + n0 + (tx << 2)) = cv;
        }
    }
}

// ---------------------------------------------------------------------------
// Workhorse (r7-proven): C[64][128] = A[64][256] @ B^T, K=256, 256 threads,
// 4x8 microtile, single-buffered.
// ---------------------------------------------------------------------------
__device__ __forceinline__ void gemm64x128_q(const float* __restrict__ A,
                                             const float* __restrict__ B,
                                             float* __restrict__ C, int ldc)
{
    __shared__ float As[16][68];
    __shared__ float Bs[16][132];

    const int tid = threadIdx.x;
    const int tx = tid & 15;
    const int ty = tid >> 4;
    const int ra  = tid >> 2;          // 0..63
    const int kqa = (tid & 3) << 2;    // 0,4,8,12
    const int rb  = tid >> 1;          // 0..127
    const int kq8 = (tid & 1) << 3;    // 0 or 8

    float acc[2][4][4];                // [colgrp g][row u][v]
    #pragma unroll
    for (int g = 0; g < 2; ++g)
        #pragma unroll
        for (int u = 0; u < 4; ++u)
            #pragma unroll
            for (int v = 0; v < 4; ++v) acc[g][u][v] = 0.f;

    for (int kk = 0; kk < 256; kk += 16) {
        float4 av = *(const float4*)(A + (size_t)ra * 256 + kk + kqa);
        As[kqa + 0][ra] = av.x; As[kqa + 1][ra] = av.y;
        As[kqa + 2][ra] = av.z; As[kqa + 3][ra] = av.w;

        const float* bp = B + (size_t)rb * 256 + kk + kq8;
        float4 b0 = *(const float4*)(bp);
        float4 b1 = *(const float4*)(bp + 4);
        Bs[kq8 + 0][rb] = b0.x; Bs[kq8 + 1][rb] = b0.y;
        Bs[kq8 + 2][rb] = b0.z; Bs[kq8 + 3][rb] = b0.w;
        Bs[kq8 + 4][rb] = b1.x; Bs[kq8 + 5][rb] = b1.y;
        Bs[kq8 + 6][rb] = b1.z; Bs[kq8 + 7][rb] = b1.w;
        __syncthreads();

        #pragma unroll
        for (int kq = 0; kq < 16; ++kq) {
            float4 a   = *(const float4*)(&As[kq][4 * ty]);
            float4 b0v = *(const float4*)(&Bs[kq][4 * tx]);
            float4 b1v = *(const float4*)(&Bs[kq][4 * tx + 64]);
            float af[4] = {a.x, a.y, a.z, a.w};
            float bf[8] = {b0v.x, b0v.y, b0v.z, b0v.w, b1v.x, b1v.y, b1v.z, b1v.w};
            #pragma unroll
            for (int g = 0; g < 2; ++g)
                #pragma unroll
                for (int u = 0; u < 4; ++u)
                    #pragma unroll
                    for (int v = 0; v < 4; ++v)
                        acc[g][u][v] = fmaf(af[u], bf[g * 4 + v], acc[g][u][v]);
        }
        __syncthreads();
    }

    #pragma unroll
    for (int u = 0; u < 4; ++u) {
        int row = 4 * ty + u;
        #pragma unroll
        for (int g = 0; g < 2; ++g) {
            float4 cv = make_float4(acc[g][u][0], acc[g][u][1],
                                    acc[g][u][2], acc[g][u][3]);
            *(float4*)(C + (size_t)row * ldc + 4 * tx + 64 * g) = cv;
        }
    }
}

// ---------------------------------------------------------------------------
// doubling level n (32x64 tiles, 2x block count of the legacy version):
//   jump  : w[2^n + r] = Apow_n @ w[r]   (n=0 reads Bv directly as w[0])
//   square: Apow_{n+1} = Apow_n @ Apow_n
// grid (4, 16, nz): x = 64-col tile, y<8 jump 32-row tiles, y>=8 square tiles.
// n==0: block (x=3,y=15) additionally writes w[0] = Bv (no reader this launch).
// ---------------------------------------------------------------------------
__global__ void k_level2(int n, int sbase, const float* A0, const float* A1,
                         const float* A2, const float* B0, const float* B1,
                         const float* B2, float* ws)
{
    int s = blockIdx.z + sbase;
    int L = 192 << s;
    const float* Ain = (s == 0) ? A0 : (s == 1) ? A1 : A2;
    const float* Bv  = (s == 0) ? B0 : (s == 1) ? B1 : B2;
    float* wbase = ws + W_OFF + off_w_f(s);
    float* bufA  = ws + AP_OFF + s * 131072;
    float* bufB  = bufA + 65536;
    const float* src = (n == 0) ? Ain : (((n - 1) & 1) ? bufB : bufA);

    const int y = blockIdx.y;
    const int n0col = blockIdx.x * 64;

    if (n == 0 && y == 15 && blockIdx.x == 3)
        ws[W_OFF + off_w_f(s) + threadIdx.x] = Bv[threadIdx.x];

    if (y < 8) {
        int p2 = 1 << n;
        if (p2 >= L) return;
        int cnt = min(p2, L - p2);
        int m0 = y * 32;
        if (m0 >= cnt) return;
        const float* Aop = (n == 0) ? Bv : wbase;   // n=0: w[0] == Bv (1 row)
        gemm_tile32<true>(Aop, src, wbase + (size_t)p2 * 256, cnt, 256, m0, n0col);
    } else {
        if ((2 << n) >= L) return;
        float* dst = (n & 1) ? bufB : bufA;
        gemm_tile32<false>(src, src, dst, 256, 256, (y - 8) * 32, n0col);
    }
}

// ---------------------------------------------------------------------------
// Wt[s][ri][k][i][o] = W[i][o][k]  — LDS-staged, fully coalesced.
// ---------------------------------------------------------------------------
__global__ void k_transpose(const float* Wr0, const float* Wi0,
                            const float* Wr1, const float* Wi1,
                            const float* Wr2, const float* Wi2, float* ws)
{
    __shared__ float t[256][33];
    int bid = blockIdx.x;
    int i  = bid & 255;
    int ri = (bid >> 8) & 1;
    int s  = bid >> 9;
    const float* W;
    if (s == 0)      W = ri ? Wi0 : Wr0;
    else if (s == 1) W = ri ? Wi1 : Wr1;
    else             W = ri ? Wi2 : Wr2;

    const int tid = threadIdx.x;
    const float* slab = W + (size_t)i * 8192;
    #pragma unroll
    for (int j = 0; j < 8; ++j) {
        int f = j * 1024 + tid * 4;
        float4 v = *(const float4*)(slab + f);
        int o = f >> 5;
        int k = f & 31;
        t[o][k + 0] = v.x; t[o][k + 1] = v.y;
        t[o][k + 2] = v.z; t[o][k + 3] = v.w;
    }
    __syncthreads();

    int sri = s * 2 + ri;
    #pragma unroll
    for (int k = 0; k < 32; ++k) {
        ws[QT_OFF + (size_t)(sri * 32 + k) * 65536 + (size_t)i * 256 + tid] = t[tid][k];
    }
}

// ---------------------------------------------------------------------------
// Y[z][p][i] = sum_o E[L-192+p][o] * Wt[z][i][o]
// grid (2, 3, 192): x = i-half (128 cols), y = p-tile, z = (s,ri,k).
// ---------------------------------------------------------------------------
__global__ void __launch_bounds__(256, 4)
k_gemm_Y5(const float* E0, const float* E1, const float* E2, float* __restrict__ ws)
{
    const int z  = blockIdx.z;                   // (s,ri,k)
    const int s  = z >> 6;
    const int L  = 192 << s;
    const int n0 = blockIdx.x * 128;             // i half
    const int m0 = blockIdx.y * 64;              // p tile
    const float* E = (s == 0) ? E0 : (s == 1) ? E1 : E2;

    const float* Ap = E + (size_t)(L - 192) * 256 + (size_t)m0 * 256;
    const float* Bp = ws + QT_OFF + (size_t)z * 65536 + (size_t)n0 * 256;
    float* Cp = ws + Y_OFF + (size_t)z * 49152 + (size_t)m0 * 256 + n0;
    gemm64x128_q(Ap, Bp, Cp, 256);
}

// ---------------------------------------------------------------------------
// Qb[s][d][n] = sum_i w[s][d][i] * Y[n][i],  n = (ri*32+k)*192+p
// grid (96, 21): x = 128-col tile of n, y = packed (s, d-tile).  256 threads.
// ---------------------------------------------------------------------------
__global__ void __launch_bounds__(256, 4)
k_gemm_Q4(float* __restrict__ ws)
{
    const int y = blockIdx.y;
    int s, yt;
    if (y < 3)      { s = 0; yt = y; }
    else if (y < 9) { s = 1; yt = y - 3; }
    else            { s = 2; yt = y - 9; }
    const int m0 = yt * 64;
    const int n0 = blockIdx.x * 128;

    const float* Ap = ws + W_OFF + off_w_f(s) + (size_t)m0 * 256;
    const float* Bp = ws + Y_OFF + (size_t)s * 3145728 + (size_t)n0 * 256;
    float* Cp = ws + QT_OFF + qoff_f(s) + (size_t)m0 * 12288 + n0;
    gemm64x128_q(Ap, Bp, Cp, 12288);
}

// ---------------------------------------------------------------------------
// Pass 1 of chunked twiddled scan: complex chunk sums (16 chunks of L/16).
// grid (16, 32, 3), block 192 (= p)
// ---------------------------------------------------------------------------
__global__ void k_scanA(float* __restrict__ ws)
{
    const int c = blockIdx.x;
    const int k = blockIdx.y;
    const int s = blockIdx.z;
    const int L = 192 << s;
    const int C = L >> 4;
    const int p = threadIdx.x;

    __shared__ float twc[768], tws[768];
    for (int m = p; m < L; m += 192) {
        float ang = -2.f * PI_F * (float)m / (float)L;
        float ss, cc; sincosf(ang, &ss, &cc);
        twc[m] = cc; tws[m] = ss;
    }
    __syncthreads();

    const float* Qr = ws + QT_OFF + qoff_f(s) + (size_t)k * 192;
    const float* Qi = Qr + 6144;

    float ar = 0.f, ai = 0.f;
    const int d0 = c * C;
    int ph = (k * d0) % L;
    for (int j = 0; j < C; ++j) {
        int d = d0 + j;
        float qr = Qr[(size_t)d * 12288 + p];
        float qi = Qi[(size_t)d * 12288 + p];
        float cc = twc[ph], sn = tws[ph];
        ar = fmaf(cc, qr, fmaf(-sn, qi, ar));
        ai = fmaf(cc, qi, fmaf( sn, qr, ai));
        ph += k; if (ph >= L) ph -= L;
    }
    size_t sb = (size_t)((s * 32 + k) * 16 + c) * 384;
    ws[S_OFF + sb + p]       = ar;
    ws[S_OFF + sb + 192 + p] = ai;
}

// ---------------------------------------------------------------------------
// Pass 2: offset from chunk sums, rescan own chunk, fold phase into F.
// grid (16, 32, 3), block 192
// ---------------------------------------------------------------------------
__global__ void k_scanB(float* __restrict__ ws)
{
    const int c = blockIdx.x;
    const int k = blockIdx.y;
    const int s = blockIdx.z;
    const int L = 192 << s;
    const int C = L >> 4;
    const int p = threadIdx.x;

    __shared__ float twc[768], tws[768];
    for (int m = p; m < L; m += 192) {
        float ang = -2.f * PI_F * (float)m / (float)L;
        float ss, cc; sincosf(ang, &ss, &cc);
        twc[m] = cc; tws[m] = ss;
    }
    __syncthreads();

    float ar = 0.f, ai = 0.f;
    size_t sbase = (size_t)(s * 32 + k) * 16 * 384;
    for (int c2 = 0; c2 < c; ++c2) {
        ar += ws[S_OFF + sbase + (size_t)c2 * 384 + p];
        ai += ws[S_OFF + sbase + (size_t)c2 * 384 + 192 + p];
    }

    const float ck = ((k == 0) ? 1.f : 2.f) / (float)L;
    const float* Qr = ws + QT_OFF + qoff_f(s) + (size_t)k * 192;
    const float* Qi = Qr + 6144;
    float* F = ws + F_OFF + foff_f(s);

    const int d0 = c * C;
    int ph = (k * d0) % L;
    int m1 = d0 + 192 - L; if (m1 < 0) m1 += L;
    int ph2 = (k * m1) % L;
    for (int j = 0; j < C; ++j) {
        int d = d0 + j;
        float qr = Qr[(size_t)d * 12288 + p];
        float qi = Qi[(size_t)d * 12288 + p];
        float cc = twc[ph], sn = tws[ph];
        ar = fmaf(cc, qr, fmaf(-sn, qi, ar));
        ai = fmaf(cc, qi, fmaf( sn, qr, ai));
        float f = ck * fmaf(twc[ph2], ar, tws[ph2] * ai);
        int sidx = L - 1 - d;
        F[((size_t)sidx * 32 + k) * 192 + p] = f;
        ph  += k; if (ph  >= L) ph  -= L;
        ph2 += k; if (ph2 >= L) ph2 -= L;
    }
}

// ---------------------------------------------------------------------------
// Fused k-reduction + scale-combine (arithmetic identical to kred+combine):
//   Ktot[tau][p] = sum_s (tau >= 768-L_s) mlp_w[s] * sum_k F[s][tau-(768-L_s)][k][p]
// grid (768), block 192
// ---------------------------------------------------------------------------
__global__ void k_kredc(float* __restrict__ ws, const float* __restrict__ mw)
{
    const int tau = blockIdx.x;
    const int p   = threadIdx.x;
    float sum = 0.f;
    #pragma unroll
    for (int s = 0; s < 3; ++s) {
        int L = 192 << s;
        int off = 768 - L;
        if (tau >= off) {
            int sidx = tau - off;
            const float* F = ws + F_OFF + foff_f(s) + (size_t)sidx * 32 * 192;
            float kt = 0.f;
            #pragma unroll
            for (int k = 0; k < 32; ++k)
                kt += F[k * 192 + p];
            sum = fmaf(mw[s], kt, sum);
        }
    }
    ws[KTOT_OFF + (size_t)tau * 192 + p] = sum;
}

// ---------------------------------------------------------------------------
__global__ void k_out(const float* __restrict__ x, const float* __restrict__ ws,
                      const float* __restrict__ mb, float* __restrict__ out)
{
    int bid = blockIdx.x;
    int b = bid / 21;
    int c = bid - b * 21;
    __shared__ float xl[768];
    for (int t = threadIdx.x; t < 768; t += 192)
        xl[t] = x[((size_t)b * 768 + t) * 21 + c];
    __syncthreads();

    int p = threadIdx.x;
    const float* K = ws + KTOT_OFF;
    float acc = 0.f;
    for (int tau = 0; tau < 768; ++tau)
        acc = fmaf(xl[tau], K[(size_t)tau * 192 + p], acc);
    out[((size_t)b * 192 + p) * 21 + c] = acc + mb[0];
}

// ---------------------------------------------------------------------------
extern "C" void kernel_launch(void* const* d_in, const int* in_sizes, int n_in,
                              void* d_out, int out_size, void* d_ws, size_t ws_size,
                              hipStream_t stream)
{
    const float* x   = (const float*)d_in[0];
    const float* A0  = (const float*)d_in[1];
    const float* B0  = (const float*)d_in[2];
    const float* E0  = (const float*)d_in[3];
    const float* Wr0 = (const float*)d_in[4];
    const float* Wi0 = (const float*)d_in[5];
    const float* A1  = (const float*)d_in[6];
    const float* B1  = (const float*)d_in[7];
    const float* E1  = (const float*)d_in[8];
    const float* Wr1 = (const float*)d_in[9];
    const float* Wi1 = (const float*)d_in[10];
    const float* A2  = (const float*)d_in[11];
    const float* B2  = (const float*)d_in[12];
    const float* E2  = (const float*)d_in[13];
    const float* Wr2 = (const float*)d_in[14];
    const float* Wi2 = (const float*)d_in[15];
    const float* mw  = (const float*)d_in[16];
    const float* mb  = (const float*)d_in[17];
    float* ws  = (float*)d_ws;
    float* out = (float*)d_out;

    if (ws_size < (size_t)WS_FLOATS * sizeof(float)) {
        hipMemsetAsync(d_out, 0, (size_t)out_size * sizeof(float), stream);
        return;
    }

    for (int n = 0; n < 8; ++n)
        k_level2<<<dim3(4, 16, 3), 256, 0, stream>>>(n, 0, A0, A1, A2, B0, B1, B2, ws);
    k_level2<<<dim3(4, 16, 2), 256, 0, stream>>>(8, 1, A0, A1, A2, B0, B1, B2, ws);
    k_level2<<<dim3(4, 16, 1), 256, 0, stream>>>(9, 2, A0, A1, A2, B0, B1, B2, ws);
    k_transpose<<<1536, 256, 0, stream>>>(Wr0, Wi0, Wr1, Wi1, Wr2, Wi2, ws);
    k_gemm_Y5<<<dim3(2, 3, 192), 256, 0, stream>>>(E0, E1, E2, ws);
    k_gemm_Q4<<<dim3(96, 21), 256, 0, stream>>>(ws);
    k_scanA<<<dim3(16, 32, 3), 192, 0, stream>>>(ws);
    k_scanB<<<dim3(16, 32, 3), 192, 0, stream>>>(ws);
    k_kredc<<<768, 192, 0, stream>>>(ws, mw);
    k_out<<<336, 192, 0, stream>>>(x, ws, mb, out);
}